// Round 1
// baseline (418.288 us; speedup 1.0000x reference)
//
#include <hip/hip_runtime.h>
#include <hip/hip_bf16.h>
#include <stdint.h>

#define BATCH 4
#define SEQ   2048
#define NHEAD 16
#define DIM   1024
#define DKV   64
#define MTOT  (BATCH*SEQ)   // 8192

typedef __attribute__((ext_vector_type(8))) short  bf16x8;
typedef __attribute__((ext_vector_type(4))) float  f32x4;
typedef unsigned short u16;
typedef unsigned int   u32;
typedef __attribute__((ext_vector_type(4))) u16 u16x4;

__device__ __forceinline__ u16 f2bf(float f) {
  u32 u = __builtin_bit_cast(u32, f);
  u32 r = (u + 0x7FFFu + ((u >> 16) & 1u)) >> 16;
  return (u16)r;
}

__device__ __forceinline__ void gload_lds16(const void* g, void* l) {
  __builtin_amdgcn_global_load_lds((u32 __attribute__((address_space(1)))*)(g),
                                   (u32 __attribute__((address_space(3)))*)(l),
                                   16, 0, 0);
}

// ---------------- conversions ----------------

__global__ void k_cvt_q(const float* __restrict__ src, u16* __restrict__ dst) {
  const int i = (blockIdx.x * 256 + threadIdx.x) * 4;
  float4 v = *(const float4*)(src + i);
  u16x4 o;
  o[0] = f2bf(v.x); o[1] = f2bf(v.y); o[2] = f2bf(v.z); o[3] = f2bf(v.w);
  *(u16x4*)(dst + i) = o;
}

// W_query/key/val: [H=16][D=1024][K=64] -> Bt layout [n=h*64+k][d]
__global__ void k_cvt_wproj(const float* __restrict__ w, u16* __restrict__ wt) {
  const int idx = blockIdx.x * 256 + threadIdx.x;   // over 1024*1024, dst-indexed
  const int n = idx >> 10, d = idx & 1023;
  wt[idx] = f2bf(w[((n >> 6) << 16) + (d << 6) + (n & 63)]);
}

// W_out: [hv=1024][e=1024] -> Bt layout [e][hv]
__global__ void k_cvt_wout(const float* __restrict__ w, u16* __restrict__ wt) {
  const int idx = blockIdx.x * 256 + threadIdx.x;
  const int e = idx >> 10, hv = idx & 1023;
  wt[idx] = f2bf(w[(hv << 10) + e]);
}

// ---------------- GEMM: C[m][n] = sum_k A[m][k] * Bt[n][k] ----------------

#define BM 128
#define BN 128
#define BK 32

template<bool F32OUT>
__device__ __forceinline__ void gemm_tile(const u16* __restrict__ A, const u16* __restrict__ Bt,
                                          void* __restrict__ Cp, int m0, int n0, int K, int N) {
  __shared__ u16 sA[BM * BK];
  __shared__ u16 sB[BN * BK];
  const int tid = threadIdx.x;
  const int wid = tid >> 6, lane = tid & 63;
  const int g = lane >> 4, li = lane & 15;
  const int wr = (wid >> 1) * 64, wc = (wid & 1) * 64;

  f32x4 acc[4][4] = {};

  for (int k0 = 0; k0 < K; k0 += BK) {
    __syncthreads();
#pragma unroll
    for (int c = 0; c < 2; ++c) {
      const int chunk = c * 256 + tid;         // 0..511, 16B each
      const int row = chunk >> 2;              // 0..127
      const int ke  = (chunk & 3) * 8;         // element offset in k
      // LDS dest is wave-uniform base; HW adds lane*16
      gload_lds16(A  + (size_t)(m0 + row) * K + k0 + ke, sA + (size_t)(c * 256 + wid * 64) * 8);
      gload_lds16(Bt + (size_t)(n0 + row) * K + k0 + ke, sB + (size_t)(c * 256 + wid * 64) * 8);
    }
    __syncthreads();

    bf16x8 af[4], bfr[4];
#pragma unroll
    for (int t = 0; t < 4; ++t) {
      af[t]  = *(const bf16x8*)(sA + (wr + t * 16 + li) * BK + g * 8);
      bfr[t] = *(const bf16x8*)(sB + (wc + t * 16 + li) * BK + g * 8);
    }
#pragma unroll
    for (int i = 0; i < 4; ++i)
#pragma unroll
      for (int j = 0; j < 4; ++j)
        acc[i][j] = __builtin_amdgcn_mfma_f32_16x16x32_bf16(af[i], bfr[j], acc[i][j], 0, 0, 0);
  }

#pragma unroll
  for (int i = 0; i < 4; ++i)
#pragma unroll
    for (int j = 0; j < 4; ++j)
#pragma unroll
      for (int r = 0; r < 4; ++r) {
        const size_t row = (size_t)(m0 + wr + i * 16 + g * 4 + r);
        const int col = n0 + wc + j * 16 + li;
        if (F32OUT) ((float*)Cp)[row * N + col] = acc[i][j][r];
        else        ((u16*)Cp)[row * N + col]   = f2bf(acc[i][j][r]);
      }
}

__global__ __launch_bounds__(256)
void k_gemm_qkv(const u16* __restrict__ A,
                const u16* __restrict__ wq, const u16* __restrict__ wk, const u16* __restrict__ wv,
                u16* __restrict__ Q, u16* __restrict__ K, u16* __restrict__ V) {
  const int m0 = blockIdx.x * BM;
  const int yt = blockIdx.y;
  const int wsel = yt >> 3;
  const int n0 = (yt & 7) * BN;
  const u16* Bt = (wsel == 0) ? wq : (wsel == 1) ? wk : wv;
  u16* C        = (wsel == 0) ? Q  : (wsel == 1) ? K  : V;
  gemm_tile<false>(A, Bt, C, m0, n0, DIM, DIM);
}

__global__ __launch_bounds__(256)
void k_gemm_out(const u16* __restrict__ A, const u16* __restrict__ Bt, float* __restrict__ C) {
  gemm_tile<true>(A, Bt, C, blockIdx.x * BM, blockIdx.y * BN, DIM, DIM);
}

// ---------------- flash attention ----------------
// grid: (SEQ/QB, BATCH*NHEAD); 4 waves, each owns 16 q rows.

#define QB   64
#define KB   64
#define PSTR 80   // padded LDS stride (160B, 16B-aligned, breaks 32-way bank conflict)

__global__ __launch_bounds__(256, 4)
void k_attn(const u16* __restrict__ Q, const u16* __restrict__ K,
            const u16* __restrict__ V, u16* __restrict__ O) {
  const int qt = blockIdx.x, bh = blockIdx.y;
  const int b = bh >> 4, h = bh & 15;
  const int q0 = qt * QB;
  const int tid = threadIdx.x, wid = tid >> 6, lane = tid & 63;
  const int g = lane >> 4, li = lane & 15;

  __shared__ u16 kl[KB][PSTR];       // K tile   [n][d]
  __shared__ u16 vt[DKV][PSTR];      // V^T tile [dv][n]
  __shared__ u16 pl[4][16][PSTR];    // per-wave P tile [q][n]

  const size_t rb = (size_t)b * SEQ;
  const int hc = h * DKV;

  // Q fragments (A operand), rows = q0 + wid*16 + li
  bf16x8 qf0, qf1;
  {
    const u16* qp = Q + (rb + q0 + wid * 16 + li) * DIM + hc + g * 8;
    qf0 = *(const bf16x8*)qp;
    qf1 = *(const bf16x8*)(qp + 32);
  }

  float mr[4] = {-3e38f, -3e38f, -3e38f, -3e38f};
  float lr[4] = {0.f, 0.f, 0.f, 0.f};
  f32x4 o[4] = {};

  for (int n0 = 0; n0 < SEQ; n0 += KB) {
    __syncthreads();   // protect kl/vt from previous iteration's readers
#pragma unroll
    for (int c = 0; c < 2; ++c) {
      const int chunk = c * 256 + tid;       // 0..511
      const int row = chunk >> 3;            // 0..63
      const int co  = (chunk & 7) * 8;       // 0..56
      const size_t gr = (rb + n0 + row) * DIM + hc + co;
      *(bf16x8*)(&kl[row][co]) = *(const bf16x8*)(K + gr);
      bf16x8 vv = *(const bf16x8*)(V + gr);
#pragma unroll
      for (int j = 0; j < 8; ++j) vt[co + j][row] = (u16)vv[j];
    }
    __syncthreads();

    // S = scale * Q K^T : D[row=4g+r][col=li], col -> kv = n0 + t*16 + li
    f32x4 s[4];
#pragma unroll
    for (int t = 0; t < 4; ++t) {
      bf16x8 kf0 = *(const bf16x8*)(&kl[t * 16 + li][g * 8]);
      bf16x8 kf1 = *(const bf16x8*)(&kl[t * 16 + li][32 + g * 8]);
      f32x4 z = {};
      z = __builtin_amdgcn_mfma_f32_16x16x32_bf16(qf0, kf0, z, 0, 0, 0);
      z = __builtin_amdgcn_mfma_f32_16x16x32_bf16(qf1, kf1, z, 0, 0, 0);
      s[t] = z * 0.125f;
    }

    // online softmax (per lane: rows 4g+r)
    float corr[4];
#pragma unroll
    for (int r = 0; r < 4; ++r) {
      float mx = fmaxf(fmaxf(s[0][r], s[1][r]), fmaxf(s[2][r], s[3][r]));
#pragma unroll
      for (int st = 1; st < 16; st <<= 1) mx = fmaxf(mx, __shfl_xor(mx, st));
      const float mn = fmaxf(mr[r], mx);
      corr[r] = __expf(mr[r] - mn);
      mr[r] = mn;
      float ps = 0.f;
#pragma unroll
      for (int t = 0; t < 4; ++t) {
        const float p = __expf(s[t][r] - mn);
        s[t][r] = p;
        ps += p;
      }
#pragma unroll
      for (int st = 1; st < 16; st <<= 1) ps += __shfl_xor(ps, st);
      lr[r] = lr[r] * corr[r] + ps;
    }

    // P (D-layout) -> LDS -> A-fragment layout
#pragma unroll
    for (int t = 0; t < 4; ++t)
#pragma unroll
      for (int r = 0; r < 4; ++r)
        pl[wid][g * 4 + r][t * 16 + li] = f2bf(s[t][r]);

    // rescale O
#pragma unroll
    for (int t = 0; t < 4; ++t) {
      o[t][0] *= corr[0]; o[t][1] *= corr[1];
      o[t][2] *= corr[2]; o[t][3] *= corr[3];
    }

    bf16x8 pf0 = *(const bf16x8*)(&pl[wid][li][g * 8]);
    bf16x8 pf1 = *(const bf16x8*)(&pl[wid][li][32 + g * 8]);
#pragma unroll
    for (int t = 0; t < 4; ++t) {
      bf16x8 vf0 = *(const bf16x8*)(&vt[t * 16 + li][g * 8]);
      bf16x8 vf1 = *(const bf16x8*)(&vt[t * 16 + li][32 + g * 8]);
      o[t] = __builtin_amdgcn_mfma_f32_16x16x32_bf16(pf0, vf0, o[t], 0, 0, 0);
      o[t] = __builtin_amdgcn_mfma_f32_16x16x32_bf16(pf1, vf1, o[t], 0, 0, 0);
    }
  }

#pragma unroll
  for (int t = 0; t < 4; ++t)
#pragma unroll
    for (int r = 0; r < 4; ++r) {
      const size_t row = rb + q0 + wid * 16 + g * 4 + r;
      O[row * DIM + hc + t * 16 + li] = f2bf(o[t][r] / lr[r]);
    }
}

// ---------------- launch ----------------

extern "C" void kernel_launch(void* const* d_in, const int* in_sizes, int n_in,
                              void* d_out, int out_size, void* d_ws, size_t ws_size,
                              hipStream_t stream) {
  (void)in_sizes; (void)n_in; (void)out_size; (void)ws_size;
  const float* q  = (const float*)d_in[0];
  const float* Wq = (const float*)d_in[1];
  const float* Wk = (const float*)d_in[2];
  const float* Wv = (const float*)d_in[3];
  const float* Wo = (const float*)d_in[4];
  float* out = (float*)d_out;

  char* p = (char*)d_ws;
  u16* qb  = (u16*)p; p += (size_t)MTOT * DIM * 2;   // 16MB
  u16* wqt = (u16*)p; p += (size_t)DIM * DIM * 2;    // 2MB
  u16* wkt = (u16*)p; p += (size_t)DIM * DIM * 2;
  u16* wvt = (u16*)p; p += (size_t)DIM * DIM * 2;
  u16* wot = (u16*)p; p += (size_t)DIM * DIM * 2;
  u16* Qb  = (u16*)p; p += (size_t)MTOT * DIM * 2;   // 16MB
  u16* Kb  = (u16*)p; p += (size_t)MTOT * DIM * 2;
  u16* Vb  = (u16*)p; p += (size_t)MTOT * DIM * 2;
  u16* Hb  = Qb;  // heads reuse Q buffer: each attn block reads its Q tile to regs first,
                  // then writes the exact same (row, col-block) range. No cross-block overlap.

  k_cvt_q<<<(MTOT * DIM / 4) / 256, 256, 0, stream>>>(q, qb);
  k_cvt_wproj<<<(DIM * DIM) / 256, 256, 0, stream>>>(Wq, wqt);
  k_cvt_wproj<<<(DIM * DIM) / 256, 256, 0, stream>>>(Wk, wkt);
  k_cvt_wproj<<<(DIM * DIM) / 256, 256, 0, stream>>>(Wv, wvt);
  k_cvt_wout<<<(DIM * DIM) / 256, 256, 0, stream>>>(Wo, wot);

  k_gemm_qkv<<<dim3(MTOT / BM, 24), 256, 0, stream>>>(qb, wqt, wkt, wvt, Qb, Kb, Vb);
  k_attn<<<dim3(SEQ / QB, BATCH * NHEAD), 256, 0, stream>>>(Qb, Kb, Vb, Hb);
  k_gemm_out<<<dim3(MTOT / BM, DIM / BN), 256, 0, stream>>>(Hb, wot, out);
}

// Round 2
// 301.765 us; speedup vs baseline: 1.3861x; 1.3861x over previous
//
#include <hip/hip_runtime.h>
#include <hip/hip_bf16.h>
#include <stdint.h>
#include <math.h>

#define BATCH 4
#define SEQ   2048
#define NHEAD 16
#define DIM   1024
#define DKV   64
#define MTOT  (BATCH*SEQ)   // 8192

typedef __attribute__((ext_vector_type(8))) short  bf16x8;
typedef __attribute__((ext_vector_type(4))) short  s16x4;
typedef __attribute__((ext_vector_type(4))) float  f32x4;
typedef unsigned short u16;
typedef unsigned int   u32;
typedef __attribute__((ext_vector_type(4))) u16 u16x4;

// 0.125 (1/sqrt(dk)) * log2(e): folded into Q so attention runs exp2-domain.
#define QSCALE 0.18033688011112042f

__device__ __forceinline__ u16 f2bf(float f) {
  u32 u = __builtin_bit_cast(u32, f);
  u32 r = (u + 0x7FFFu + ((u >> 16) & 1u)) >> 16;
  return (u16)r;
}

__device__ __forceinline__ void gload_lds16(const void* g, void* l) {
  __builtin_amdgcn_global_load_lds((u32 __attribute__((address_space(1)))*)(g),
                                   (u32 __attribute__((address_space(3)))*)(l),
                                   16, 0, 0);
}

// ---------------- conversions ----------------

__global__ void k_cvt_q(const float* __restrict__ src, u16* __restrict__ dst) {
  const int i = (blockIdx.x * 256 + threadIdx.x) * 4;
  float4 v = *(const float4*)(src + i);
  u16x4 o;
  o[0] = f2bf(v.x); o[1] = f2bf(v.y); o[2] = f2bf(v.z); o[3] = f2bf(v.w);
  *(u16x4*)(dst + i) = o;
}

// W_query/key/val: [H=16][D=1024][K=64] -> Bt layout [n=h*64+k][d]
__global__ void k_cvt_wproj(const float* __restrict__ w, u16* __restrict__ wt) {
  const int idx = blockIdx.x * 256 + threadIdx.x;
  const int n = idx >> 10, d = idx & 1023;
  wt[idx] = f2bf(w[((n >> 6) << 16) + (d << 6) + (n & 63)]);
}

// W_out: [hv=1024][e=1024] -> Bt layout [e][hv]
__global__ void k_cvt_wout(const float* __restrict__ w, u16* __restrict__ wt) {
  const int idx = blockIdx.x * 256 + threadIdx.x;
  const int e = idx >> 10, hv = idx & 1023;
  wt[idx] = f2bf(w[(hv << 10) + e]);
}

// ---------------- GEMM: C[m][n] = sum_k A[m][k] * Bt[n][k] ----------------
// MODE: 0 = bf16 natural, 1 = f32 natural, 2 = bf16 natural * QSCALE, 3 = bf16 transposed [n][MTOT]

#define BM 128
#define BN 128
#define BK 32

template<int MODE>
__device__ __forceinline__ void gemm_tile(const u16* __restrict__ A, const u16* __restrict__ Bt,
                                          void* __restrict__ Cp, int m0, int n0, int K, int N) {
  __shared__ u16 sA[BM * BK];
  __shared__ u16 sB[BN * BK];
  const int tid = threadIdx.x;
  const int wid = tid >> 6, lane = tid & 63;
  const int g = lane >> 4, li = lane & 15;
  const int wr = (wid >> 1) * 64, wc = (wid & 1) * 64;

  f32x4 acc[4][4] = {};

  for (int k0 = 0; k0 < K; k0 += BK) {
    __syncthreads();
#pragma unroll
    for (int c = 0; c < 2; ++c) {
      const int chunk = c * 256 + tid;
      const int row = chunk >> 2;
      const int ke  = (chunk & 3) * 8;
      gload_lds16(A  + (size_t)(m0 + row) * K + k0 + ke, sA + (size_t)(c * 256 + wid * 64) * 8);
      gload_lds16(Bt + (size_t)(n0 + row) * K + k0 + ke, sB + (size_t)(c * 256 + wid * 64) * 8);
    }
    __syncthreads();

    bf16x8 af[4], bfr[4];
#pragma unroll
    for (int t = 0; t < 4; ++t) {
      af[t]  = *(const bf16x8*)(sA + (wr + t * 16 + li) * BK + g * 8);
      bfr[t] = *(const bf16x8*)(sB + (wc + t * 16 + li) * BK + g * 8);
    }
#pragma unroll
    for (int i = 0; i < 4; ++i)
#pragma unroll
      for (int j = 0; j < 4; ++j)
        acc[i][j] = __builtin_amdgcn_mfma_f32_16x16x32_bf16(af[i], bfr[j], acc[i][j], 0, 0, 0);
  }

#pragma unroll
  for (int i = 0; i < 4; ++i)
#pragma unroll
    for (int j = 0; j < 4; ++j) {
      if (MODE == 3) {
        const int col = n0 + wc + j * 16 + li;
        const size_t rowb = (size_t)(m0 + wr + i * 16 + g * 4);
        u16x4 w;
#pragma unroll
        for (int r = 0; r < 4; ++r) w[r] = f2bf(acc[i][j][r]);
        *(u16x4*)((u16*)Cp + (size_t)col * MTOT + rowb) = w;
      } else {
#pragma unroll
        for (int r = 0; r < 4; ++r) {
          const size_t row = (size_t)(m0 + wr + i * 16 + g * 4 + r);
          const int col = n0 + wc + j * 16 + li;
          float v = acc[i][j][r];
          if (MODE == 2) v *= QSCALE;
          if (MODE == 1) ((float*)Cp)[row * N + col] = v;
          else           ((u16*)Cp)[row * N + col]   = f2bf(v);
        }
      }
    }
}

__global__ __launch_bounds__(256)
void k_gemm_qkv(const u16* __restrict__ A,
                const u16* __restrict__ wq, const u16* __restrict__ wk, const u16* __restrict__ wv,
                u16* __restrict__ Qo, u16* __restrict__ Ko, u16* __restrict__ Vto) {
  const int m0 = blockIdx.x * BM;
  const int yt = blockIdx.y;
  const int wsel = yt >> 3;
  const int n0 = (yt & 7) * BN;
  if (wsel == 0)      gemm_tile<2>(A, wq, Qo,  m0, n0, DIM, DIM);   // Q, pre-scaled
  else if (wsel == 1) gemm_tile<0>(A, wk, Ko,  m0, n0, DIM, DIM);   // K natural
  else                gemm_tile<3>(A, wv, Vto, m0, n0, DIM, DIM);   // V^T [n][MTOT]
}

__global__ __launch_bounds__(256)
void k_gemm_out(const u16* __restrict__ A, const u16* __restrict__ Bt, float* __restrict__ C) {
  gemm_tile<1>(A, Bt, C, blockIdx.x * BM, blockIdx.y * BN, DIM, DIM);
}

// ---------------- flash attention ----------------
// grid: (SEQ/128, BATCH*NHEAD); 4 waves, each owns 32 q rows (2 row-tiles).
// Swapped QK^T (S^T = K·Q^T): lane (g,li) holds S[q=li][kv=16t+4g+r] -> softmax lane-local.
// PV as O^T = V^T·P^T with permuted k-order so P stays in registers (no LDS round-trip).
// K and V^T tiles staged via global_load_lds, linear LDS dest + pre-swizzled source
// (slot ^= row&7) -> conflict-free swizzled ds_read. Double-buffered, prefetch 1 tile ahead.

#define KB 64
#define NT (SEQ/KB)

__global__ __launch_bounds__(256)
void k_attn(const u16* __restrict__ Q, const u16* __restrict__ K,
            const u16* __restrict__ Vt, u16* __restrict__ O) {
  const int qt = blockIdx.x, bh = blockIdx.y;
  const int b = bh >> 4, h = bh & 15;
  const int q0 = qt * 128;
  const int tid = threadIdx.x, wid = tid >> 6, lane = tid & 63;
  const int g = lane >> 4, li = lane & 15;

  __shared__ u16 kl[2][KB * 64];    // K tile  [kv][d], swizzled
  __shared__ u16 vl[2][64 * KB];    // V^T tile [dv][kv], swizzled

  const size_t rb = (size_t)b * SEQ;
  const int hc = h * DKV;

  // Q fragments (B-operand: lane holds Q[q=li][d=g*8+j]), u=0,1 row-tiles
  bf16x8 qf[2][2];
#pragma unroll
  for (int u = 0; u < 2; ++u) {
    const u16* qp = Q + (rb + q0 + wid * 32 + u * 16 + li) * DIM + hc;
    qf[u][0] = *(const bf16x8*)(qp + g * 8);
    qf[u][1] = *(const bf16x8*)(qp + 32 + g * 8);
  }

  float mrun[2] = {-1e30f, -1e30f};
  float lrun[2] = {0.f, 0.f};
  f32x4 o[2][4] = {};

  const int r8  = lane >> 3;
  const int swz = ((lane & 7) ^ r8) * 8;   // pre-swizzled source element offset

  // prologue: stage tile 0 into buffer 0
#pragma unroll
  for (int c = 0; c < 2; ++c) {
    const int row = (c * 4 + wid) * 8 + r8;
    gload_lds16(K  + (rb + row) * DIM + hc + swz,            &kl[0][(c * 4 + wid) * 512]);
    gload_lds16(Vt + (size_t)(hc + row) * MTOT + rb + swz,   &vl[0][(c * 4 + wid) * 512]);
  }

  for (int it = 0; it < NT; ++it) {
    const int cur = it & 1;
    __syncthreads();   // drains vmcnt: buf[cur] staged; prev compute done with buf[cur]

    if (it + 1 < NT) {           // prefetch next tile into other buffer
      const int n1 = (it + 1) * KB;
#pragma unroll
      for (int c = 0; c < 2; ++c) {
        const int row = (c * 4 + wid) * 8 + r8;
        gload_lds16(K  + (rb + n1 + row) * DIM + hc + swz,          &kl[cur ^ 1][(c * 4 + wid) * 512]);
        gload_lds16(Vt + (size_t)(hc + row) * MTOT + rb + n1 + swz, &vl[cur ^ 1][(c * 4 + wid) * 512]);
      }
    }

    const u16* kb = kl[cur];
    const u16* vb = vl[cur];
    const int sw = (li & 7) << 3;

    // S^T = K·Q^T : lane (g,li) reg r of s[u][t] = S[q=li][kv = 16t+4g+r]
    f32x4 s[2][4];
#pragma unroll
    for (int t = 0; t < 4; ++t) {
      const int row = t * 16 + li;
      bf16x8 kf0 = *(const bf16x8*)(kb + row * 64 + ((g * 8) ^ sw));
      bf16x8 kf1 = *(const bf16x8*)(kb + row * 64 + ((32 + g * 8) ^ sw));
#pragma unroll
      for (int u = 0; u < 2; ++u) {
        f32x4 z = {};
        z = __builtin_amdgcn_mfma_f32_16x16x32_bf16(kf0, qf[u][0], z, 0, 0, 0);
        z = __builtin_amdgcn_mfma_f32_16x16x32_bf16(kf1, qf[u][1], z, 0, 0, 0);
        s[u][t] = z;
      }
    }

    // online softmax (exp2 domain; scale folded into Q) + in-register P pack
    bf16x8 pa[2][2];
    float corr[2];
#pragma unroll
    for (int u = 0; u < 2; ++u) {
      float pmax = s[u][0][0];
#pragma unroll
      for (int t = 0; t < 4; ++t)
#pragma unroll
        for (int r = 0; r < 4; ++r) pmax = fmaxf(pmax, s[u][t][r]);
      pmax = fmaxf(pmax, __shfl_xor(pmax, 16));
      pmax = fmaxf(pmax, __shfl_xor(pmax, 32));
      const float mn = fmaxf(mrun[u], pmax);
      corr[u] = exp2f(mrun[u] - mn);
      mrun[u] = mn;
      float ps = 0.f;
#pragma unroll
      for (int t = 0; t < 4; ++t)
#pragma unroll
        for (int r = 0; r < 4; ++r) {
          const float p = exp2f(s[u][t][r] - mn);
          s[u][t][r] = p;
          ps += p;
        }
      ps += __shfl_xor(ps, 16);
      ps += __shfl_xor(ps, 32);
      lrun[u] = lrun[u] * corr[u] + ps;
      // A/B k-order permutation sigma_h(g,j) = 32h + 16*(j>>2) + 4g + (j&3):
      // P word j of half h = lane's own p[t=2h+(j>>2)][r=j&3]
#pragma unroll
      for (int hh = 0; hh < 2; ++hh)
#pragma unroll
        for (int j = 0; j < 8; ++j)
          pa[u][hh][j] = (short)f2bf(s[u][2 * hh + (j >> 2)][j & 3]);
#pragma unroll
      for (int t = 0; t < 4; ++t) o[u][t] *= corr[u];
    }

    // O^T += V^T · P^T with matching permuted k-order on the V^T fragment
#pragma unroll
    for (int t = 0; t < 4; ++t) {
      const int row = t * 16 + li;
#pragma unroll
      for (int hh = 0; hh < 2; ++hh) {
        s16x4 vA = *(const s16x4*)(vb + row * 64 + ((32 * hh + 4 * g) ^ sw));
        s16x4 vB = *(const s16x4*)(vb + row * 64 + ((32 * hh + 16 + 4 * g) ^ sw));
        bf16x8 vf;
        vf[0] = vA[0]; vf[1] = vA[1]; vf[2] = vA[2]; vf[3] = vA[3];
        vf[4] = vB[0]; vf[5] = vB[1]; vf[6] = vB[2]; vf[7] = vB[3];
#pragma unroll
        for (int u = 0; u < 2; ++u)
          o[u][t] = __builtin_amdgcn_mfma_f32_16x16x32_bf16(vf, pa[u][hh], o[u][t], 0, 0, 0);
      }
    }
  }

  // epilogue: lane (g,li) holds O[q=li][dv = 16t+4g+r]
#pragma unroll
  for (int u = 0; u < 2; ++u) {
    const float inv = 1.0f / lrun[u];
    const size_t qrow = rb + q0 + wid * 32 + u * 16 + li;
#pragma unroll
    for (int t = 0; t < 4; ++t) {
      u16x4 w;
#pragma unroll
      for (int r = 0; r < 4; ++r) w[r] = f2bf(o[u][t][r] * inv);
      *(u16x4*)(O + qrow * DIM + hc + t * 16 + 4 * g) = w;
    }
  }
}

// ---------------- launch ----------------

extern "C" void kernel_launch(void* const* d_in, const int* in_sizes, int n_in,
                              void* d_out, int out_size, void* d_ws, size_t ws_size,
                              hipStream_t stream) {
  (void)in_sizes; (void)n_in; (void)out_size; (void)ws_size;
  const float* q  = (const float*)d_in[0];
  const float* Wq = (const float*)d_in[1];
  const float* Wk = (const float*)d_in[2];
  const float* Wv = (const float*)d_in[3];
  const float* Wo = (const float*)d_in[4];
  float* out = (float*)d_out;

  char* p = (char*)d_ws;
  u16* qb  = (u16*)p; p += (size_t)MTOT * DIM * 2;   // 16MB
  u16* wqt = (u16*)p; p += (size_t)DIM * DIM * 2;    // 2MB
  u16* wkt = (u16*)p; p += (size_t)DIM * DIM * 2;
  u16* wvt = (u16*)p; p += (size_t)DIM * DIM * 2;
  u16* wot = (u16*)p; p += (size_t)DIM * DIM * 2;
  u16* Qb  = (u16*)p; p += (size_t)MTOT * DIM * 2;   // 16MB (pre-scaled Q)
  u16* Kb  = (u16*)p; p += (size_t)MTOT * DIM * 2;   // 16MB
  u16* Vtb = (u16*)p; p += (size_t)MTOT * DIM * 2;   // 16MB, [n=h*64+dv][m]
  u16* Hb  = Qb;  // heads reuse Q buffer: each attn block reads its Q tile to regs
                  // before writing the exact same (rows, col-block) region.

  k_cvt_q<<<(MTOT * DIM / 4) / 256, 256, 0, stream>>>(q, qb);
  k_cvt_wproj<<<(DIM * DIM) / 256, 256, 0, stream>>>(Wq, wqt);
  k_cvt_wproj<<<(DIM * DIM) / 256, 256, 0, stream>>>(Wk, wkt);
  k_cvt_wproj<<<(DIM * DIM) / 256, 256, 0, stream>>>(Wv, wvt);
  k_cvt_wout<<<(DIM * DIM) / 256, 256, 0, stream>>>(Wo, wot);

  k_gemm_qkv<<<dim3(MTOT / BM, 24), 256, 0, stream>>>(qb, wqt, wkt, wvt, Qb, Kb, Vtb);
  k_attn<<<dim3(SEQ / 128, BATCH * NHEAD), 256, 0, stream>>>(Qb, Kb, Vtb, Hb);
  k_gemm_out<<<dim3(MTOT / BM, DIM / BN), 256, 0, stream>>>(Hb, wot, out);
}

// Round 4
// 287.616 us; speedup vs baseline: 1.4543x; 1.0492x over previous
//
#include <hip/hip_runtime.h>
#include <hip/hip_bf16.h>
#include <stdint.h>
#include <math.h>

#define BATCH 4
#define SEQ   2048
#define NHEAD 16
#define DIM   1024
#define DKV   64
#define MTOT  (BATCH*SEQ)   // 8192

typedef __attribute__((ext_vector_type(8))) short  bf16x8;
typedef __attribute__((ext_vector_type(4))) short  s16x4;
typedef __attribute__((ext_vector_type(4))) float  f32x4;
typedef unsigned short u16;
typedef unsigned int   u32;
typedef __attribute__((ext_vector_type(4))) u16 u16x4;
typedef __attribute__((ext_vector_type(2))) u32 u32x2;
typedef __attribute__((ext_vector_type(4))) u32 u32x4;

// 0.125 (1/sqrt(dk)) * log2(e): folded into Q so attention runs exp2-domain.
#define QSCALE 0.18033688011112042f
#define THR    8.0f

__device__ __forceinline__ u16 f2bf(float f) {
  __hip_bfloat16 h = __float2bfloat16(f);
  u16 r;
  __builtin_memcpy(&r, &h, 2);
  return r;
}
// packed pair -> one v_cvt_pk_bf16_f32 (compiler-generated; guide m240)
__device__ __forceinline__ u32 pkbf(float lo, float hi) {
  __hip_bfloat162 h = __float22bfloat162_rn(float2{lo, hi});
  u32 r;
  __builtin_memcpy(&r, &h, 4);
  return r;
}

__device__ __forceinline__ void gload_lds16(const void* g, void* l) {
  __builtin_amdgcn_global_load_lds((u32 __attribute__((address_space(1)))*)(g),
                                   (u32 __attribute__((address_space(3)))*)(l),
                                   16, 0, 0);
}

// ---------------- conversions ----------------

__global__ void k_cvt_q(const float* __restrict__ src, u16* __restrict__ dst) {
  const int i = (blockIdx.x * 256 + threadIdx.x) * 4;
  float4 v = *(const float4*)(src + i);
  u32x2 o;
  o[0] = pkbf(v.x, v.y); o[1] = pkbf(v.z, v.w);
  *(u32x2*)(dst + i) = o;
}

// W_query/key/val: [H=16][D=1024][K=64] -> Bt layout [n=h*64+k][d]
__global__ void k_cvt_wproj(const float* __restrict__ w, u16* __restrict__ wt) {
  const int idx = blockIdx.x * 256 + threadIdx.x;
  const int n = idx >> 10, d = idx & 1023;
  wt[idx] = f2bf(w[((n >> 6) << 16) + (d << 6) + (n & 63)]);
}

// W_out: [hv=1024][e=1024] -> Bt layout [e][hv]
__global__ void k_cvt_wout(const float* __restrict__ w, u16* __restrict__ wt) {
  const int idx = blockIdx.x * 256 + threadIdx.x;
  const int e = idx >> 10, hv = idx & 1023;
  wt[idx] = f2bf(w[(hv << 10) + e]);
}

// ---------------- GEMM: C[m][n] = sum_k A[m][k] * Bt[n][k] ----------------
// MODE: 0 = bf16 natural, 1 = f32 natural, 2 = bf16 natural * QSCALE, 3 = bf16 transposed [n][MTOT]

#define BM 128
#define BN 128
#define BK 32

template<int MODE>
__device__ __forceinline__ void gemm_tile(const u16* __restrict__ A, const u16* __restrict__ Bt,
                                          void* __restrict__ Cp, int m0, int n0, int K, int N) {
  __shared__ u16 sA[BM * BK];
  __shared__ u16 sB[BN * BK];
  const int tid = threadIdx.x;
  const int wid = tid >> 6, lane = tid & 63;
  const int g = lane >> 4, li = lane & 15;
  const int wr = (wid >> 1) * 64, wc = (wid & 1) * 64;

  f32x4 acc[4][4] = {};

  for (int k0 = 0; k0 < K; k0 += BK) {
    __syncthreads();
#pragma unroll
    for (int c = 0; c < 2; ++c) {
      const int chunk = c * 256 + tid;
      const int row = chunk >> 2;
      const int ke  = (chunk & 3) * 8;
      gload_lds16(A  + (size_t)(m0 + row) * K + k0 + ke, sA + (size_t)(c * 256 + wid * 64) * 8);
      gload_lds16(Bt + (size_t)(n0 + row) * K + k0 + ke, sB + (size_t)(c * 256 + wid * 64) * 8);
    }
    __syncthreads();

    bf16x8 af[4], bfr[4];
#pragma unroll
    for (int t = 0; t < 4; ++t) {
      af[t]  = *(const bf16x8*)(sA + (wr + t * 16 + li) * BK + g * 8);
      bfr[t] = *(const bf16x8*)(sB + (wc + t * 16 + li) * BK + g * 8);
    }
    __builtin_amdgcn_s_setprio(1);
#pragma unroll
    for (int i = 0; i < 4; ++i)
#pragma unroll
      for (int j = 0; j < 4; ++j)
        acc[i][j] = __builtin_amdgcn_mfma_f32_16x16x32_bf16(af[i], bfr[j], acc[i][j], 0, 0, 0);
    __builtin_amdgcn_s_setprio(0);
  }

#pragma unroll
  for (int i = 0; i < 4; ++i)
#pragma unroll
    for (int j = 0; j < 4; ++j) {
      if (MODE == 3) {
        const int col = n0 + wc + j * 16 + li;
        const size_t rowb = (size_t)(m0 + wr + i * 16 + g * 4);
        u32x2 w;
        w[0] = pkbf(acc[i][j][0], acc[i][j][1]);
        w[1] = pkbf(acc[i][j][2], acc[i][j][3]);
        *(u32x2*)((u16*)Cp + (size_t)col * MTOT + rowb) = w;
      } else if (MODE == 1) {
#pragma unroll
        for (int r = 0; r < 4; ++r) {
          const size_t row = (size_t)(m0 + wr + i * 16 + g * 4 + r);
          ((float*)Cp)[row * N + n0 + wc + j * 16 + li] = acc[i][j][r];
        }
      } else {
#pragma unroll
        for (int r = 0; r < 4; ++r) {
          const size_t row = (size_t)(m0 + wr + i * 16 + g * 4 + r);
          float v = acc[i][j][r];
          if (MODE == 2) v *= QSCALE;
          ((u16*)Cp)[row * N + n0 + wc + j * 16 + li] = f2bf(v);
        }
      }
    }
}

__global__ __launch_bounds__(256)
void k_gemm_qkv(const u16* __restrict__ A,
                const u16* __restrict__ wq, const u16* __restrict__ wk, const u16* __restrict__ wv,
                u16* __restrict__ Qo, u16* __restrict__ Ko, u16* __restrict__ Vto) {
  const int m0 = blockIdx.x * BM;
  const int yt = blockIdx.y;
  const int wsel = yt >> 3;
  const int n0 = (yt & 7) * BN;
  if (wsel == 0)      gemm_tile<2>(A, wq, Qo,  m0, n0, DIM, DIM);   // Q, pre-scaled
  else if (wsel == 1) gemm_tile<0>(A, wk, Ko,  m0, n0, DIM, DIM);   // K natural
  else                gemm_tile<3>(A, wv, Vto, m0, n0, DIM, DIM);   // V^T [n][MTOT]
}

__global__ __launch_bounds__(256)
void k_gemm_out(const u16* __restrict__ A, const u16* __restrict__ Bt, float* __restrict__ C) {
  gemm_tile<1>(A, Bt, C, blockIdx.x * BM, blockIdx.y * BN, DIM, DIM);
}

// ---------------- flash attention ----------------
// grid: (SEQ/128, BATCH*NHEAD); 4 waves, each owns 32 q rows (2 row-tiles).
// Swapped QK^T (S^T = K·Q^T): lane (g,li) holds S[q=li][kv=16t+4g+r] -> softmax lane-local.
// PV as O^T = V^T·P^T with permuted k-order so P stays in registers.
// K/V^T staged via global_load_lds, linear dest + pre-swizzled source -> conflict-free-ish reads.
// Double-buffered prefetch; defer-max (THR=8); cvt_pk packing; setprio around MFMA.

#define KB 64
#define NT (SEQ/KB)

__global__ __launch_bounds__(256, 4)
void k_attn(const u16* __restrict__ Q, const u16* __restrict__ K,
            const u16* __restrict__ Vt, u16* __restrict__ O) {
  const int qt = blockIdx.x, bh = blockIdx.y;
  const int b = bh >> 4, h = bh & 15;
  const int q0 = qt * 128;
  const int tid = threadIdx.x, wid = tid >> 6, lane = tid & 63;
  const int g = lane >> 4, li = lane & 15;

  __shared__ u16 kl[2][KB * 64];    // K tile  [kv][d], swizzled
  __shared__ u16 vl[2][64 * KB];    // V^T tile [dv][kv], swizzled

  const size_t rb = (size_t)b * SEQ;
  const int hc = h * DKV;

  bf16x8 qf[2][2];
#pragma unroll
  for (int u = 0; u < 2; ++u) {
    const u16* qp = Q + (rb + q0 + wid * 32 + u * 16 + li) * DIM + hc;
    qf[u][0] = *(const bf16x8*)(qp + g * 8);
    qf[u][1] = *(const bf16x8*)(qp + 32 + g * 8);
  }

  float mrun[2] = {-1e30f, -1e30f};
  float lrun[2] = {0.f, 0.f};
  f32x4 o[2][4] = {};

  const int r8  = lane >> 3;
  const int swz = ((lane & 7) ^ r8) * 8;

  // prologue: stage tile 0 into buffer 0
#pragma unroll
  for (int c = 0; c < 2; ++c) {
    const int row = (c * 4 + wid) * 8 + r8;
    gload_lds16(K  + (rb + row) * DIM + hc + swz,            &kl[0][(c * 4 + wid) * 512]);
    gload_lds16(Vt + (size_t)(hc + row) * MTOT + rb + swz,   &vl[0][(c * 4 + wid) * 512]);
  }

  for (int it = 0; it < NT; ++it) {
    const int cur = it & 1;
    __syncthreads();

    if (it + 1 < NT) {
      const int n1 = (it + 1) * KB;
#pragma unroll
      for (int c = 0; c < 2; ++c) {
        const int row = (c * 4 + wid) * 8 + r8;
        gload_lds16(K  + (rb + n1 + row) * DIM + hc + swz,          &kl[cur ^ 1][(c * 4 + wid) * 512]);
        gload_lds16(Vt + (size_t)(hc + row) * MTOT + rb + n1 + swz, &vl[cur ^ 1][(c * 4 + wid) * 512]);
      }
    }

    const u16* kb = kl[cur];
    const u16* vb = vl[cur];
    const int sw = (li & 7) << 3;

    // S^T = K·Q^T : lane (g,li) reg r of s[u][t] = S[q=li][kv = 16t+4g+r]
    f32x4 s[2][4];
    __builtin_amdgcn_s_setprio(1);
#pragma unroll
    for (int t = 0; t < 4; ++t) {
      const int row = t * 16 + li;
      bf16x8 kf0 = *(const bf16x8*)(kb + row * 64 + ((g * 8) ^ sw));
      bf16x8 kf1 = *(const bf16x8*)(kb + row * 64 + ((32 + g * 8) ^ sw));
#pragma unroll
      for (int u = 0; u < 2; ++u) {
        f32x4 z = {};
        z = __builtin_amdgcn_mfma_f32_16x16x32_bf16(kf0, qf[u][0], z, 0, 0, 0);
        z = __builtin_amdgcn_mfma_f32_16x16x32_bf16(kf1, qf[u][1], z, 0, 0, 0);
        s[u][t] = z;
      }
    }
    __builtin_amdgcn_s_setprio(0);

    // online softmax (exp2 domain), defer-max, in-register cvt_pk P pack
    bf16x8 pa[2][2];
#pragma unroll
    for (int u = 0; u < 2; ++u) {
      float m0_ = fmaxf(fmaxf(s[u][0][0], s[u][0][1]), fmaxf(s[u][0][2], s[u][0][3]));
      float m1_ = fmaxf(fmaxf(s[u][1][0], s[u][1][1]), fmaxf(s[u][1][2], s[u][1][3]));
      float m2_ = fmaxf(fmaxf(s[u][2][0], s[u][2][1]), fmaxf(s[u][2][2], s[u][2][3]));
      float m3_ = fmaxf(fmaxf(s[u][3][0], s[u][3][1]), fmaxf(s[u][3][2], s[u][3][3]));
      float pmax = fmaxf(fmaxf(m0_, m1_), fmaxf(m2_, m3_));
      pmax = fmaxf(pmax, __shfl_xor(pmax, 16));
      pmax = fmaxf(pmax, __shfl_xor(pmax, 32));
      if (__any(pmax - mrun[u] > THR)) {     // T13 defer-max: rescale only when needed
        const float mn = fmaxf(mrun[u], pmax);
        const float corr = exp2f(mrun[u] - mn);
        mrun[u] = mn;
        lrun[u] *= corr;
#pragma unroll
        for (int t = 0; t < 4; ++t) o[u][t] *= corr;
      }
      const float mb = mrun[u];
      float ps = 0.f;
#pragma unroll
      for (int t = 0; t < 4; ++t)
#pragma unroll
        for (int r = 0; r < 4; ++r) {
          const float p = exp2f(s[u][t][r] - mb);
          s[u][t][r] = p;
          ps += p;
        }
      ps += __shfl_xor(ps, 16);
      ps += __shfl_xor(ps, 32);
      lrun[u] += ps;
      // pack: pa word j of half hh = p[t=2hh+(j>>2)][r=j&3]; pairs are adjacent -> cvt_pk
#pragma unroll
      for (int hh = 0; hh < 2; ++hh) {
        u32x4 pw;
        pw[0] = pkbf(s[u][2 * hh][0],     s[u][2 * hh][1]);
        pw[1] = pkbf(s[u][2 * hh][2],     s[u][2 * hh][3]);
        pw[2] = pkbf(s[u][2 * hh + 1][0], s[u][2 * hh + 1][1]);
        pw[3] = pkbf(s[u][2 * hh + 1][2], s[u][2 * hh + 1][3]);
        pa[u][hh] = __builtin_bit_cast(bf16x8, pw);
      }
    }

    // O^T += V^T · P^T with matching permuted k-order on the V^T fragment
    __builtin_amdgcn_s_setprio(1);
#pragma unroll
    for (int t = 0; t < 4; ++t) {
      const int row = t * 16 + li;
#pragma unroll
      for (int hh = 0; hh < 2; ++hh) {
        u32x2 a = *(const u32x2*)(vb + row * 64 + ((32 * hh + 4 * g) ^ sw));
        u32x2 bq = *(const u32x2*)(vb + row * 64 + ((32 * hh + 16 + 4 * g) ^ sw));
        u32x4 w; w[0] = a[0]; w[1] = a[1]; w[2] = bq[0]; w[3] = bq[1];
        bf16x8 vf = __builtin_bit_cast(bf16x8, w);
#pragma unroll
        for (int u = 0; u < 2; ++u)
          o[u][t] = __builtin_amdgcn_mfma_f32_16x16x32_bf16(vf, pa[u][hh], o[u][t], 0, 0, 0);
      }
    }
    __builtin_amdgcn_s_setprio(0);
  }

  // epilogue: lane (g,li) holds O[q=li][dv = 16t+4g+r]
#pragma unroll
  for (int u = 0; u < 2; ++u) {
    const float inv = 1.0f / lrun[u];
    const size_t qrow = rb + q0 + wid * 32 + u * 16 + li;
#pragma unroll
    for (int t = 0; t < 4; ++t) {
      u32x2 w;
      w[0] = pkbf(o[u][t][0] * inv, o[u][t][1] * inv);
      w[1] = pkbf(o[u][t][2] * inv, o[u][t][3] * inv);
      *(u32x2*)(O + qrow * DIM + hc + t * 16 + 4 * g) = w;
    }
  }
}

// ---------------- launch ----------------

extern "C" void kernel_launch(void* const* d_in, const int* in_sizes, int n_in,
                              void* d_out, int out_size, void* d_ws, size_t ws_size,
                              hipStream_t stream) {
  (void)in_sizes; (void)n_in; (void)out_size; (void)ws_size;
  const float* q  = (const float*)d_in[0];
  const float* Wq = (const float*)d_in[1];
  const float* Wk = (const float*)d_in[2];
  const float* Wv = (const float*)d_in[3];
  const float* Wo = (const float*)d_in[4];
  float* out = (float*)d_out;

  char* p = (char*)d_ws;
  u16* qb  = (u16*)p; p += (size_t)MTOT * DIM * 2;   // 16MB
  u16* wqt = (u16*)p; p += (size_t)DIM * DIM * 2;    // 2MB
  u16* wkt = (u16*)p; p += (size_t)DIM * DIM * 2;
  u16* wvt = (u16*)p; p += (size_t)DIM * DIM * 2;
  u16* wot = (u16*)p; p += (size_t)DIM * DIM * 2;
  u16* Qb  = (u16*)p; p += (size_t)MTOT * DIM * 2;   // 16MB (pre-scaled Q)
  u16* Kb  = (u16*)p; p += (size_t)MTOT * DIM * 2;   // 16MB
  u16* Vtb = (u16*)p; p += (size_t)MTOT * DIM * 2;   // 16MB, [n=h*64+dv][m]
  u16* Hb  = Qb;  // heads reuse Q buffer (attn reads its Q tile to regs before writing same region)

  k_cvt_q<<<(MTOT * DIM / 4) / 256, 256, 0, stream>>>(q, qb);
  k_cvt_wproj<<<(DIM * DIM) / 256, 256, 0, stream>>>(Wq, wqt);
  k_cvt_wproj<<<(DIM * DIM) / 256, 256, 0, stream>>>(Wk, wkt);
  k_cvt_wproj<<<(DIM * DIM) / 256, 256, 0, stream>>>(Wv, wvt);
  k_cvt_wout<<<(DIM * DIM) / 256, 256, 0, stream>>>(Wo, wot);

  k_gemm_qkv<<<dim3(MTOT / BM, 24), 256, 0, stream>>>(qb, wqt, wkt, wvt, Qb, Kb, Vtb);
  k_attn<<<dim3(SEQ / 128, BATCH * NHEAD), 256, 0, stream>>>(Qb, Kb, Vtb, Hb);
  k_gemm_out<<<dim3(MTOT / BM, DIM / BN), 256, 0, stream>>>(Hb, wot, out);
}

// Round 5
// 248.352 us; speedup vs baseline: 1.6843x; 1.1581x over previous
//
#include <hip/hip_runtime.h>
#include <hip/hip_bf16.h>
#include <stdint.h>
#include <math.h>

#define BATCH 4
#define SEQ   2048
#define NHEAD 16
#define DIM   1024
#define DKV   64
#define MTOT  (BATCH*SEQ)   // 8192

typedef __attribute__((ext_vector_type(8))) short  bf16x8;
typedef __attribute__((ext_vector_type(4))) float  f32x4;
typedef unsigned short u16;
typedef unsigned int   u32;
typedef __attribute__((ext_vector_type(4))) u16 u16x4;
typedef __attribute__((ext_vector_type(2))) u32 u32x2;
typedef __attribute__((ext_vector_type(4))) u32 u32x4;

// 0.125 (1/sqrt(dk)) * log2(e): folded into Q so attention runs exp2-domain.
#define QSCALE 0.18033688011112042f
#define THR    8.0f

__device__ __forceinline__ u16 f2bf(float f) {
  __hip_bfloat16 h = __float2bfloat16(f);
  u16 r;
  __builtin_memcpy(&r, &h, 2);
  return r;
}
// packed pair -> one v_cvt_pk_bf16_f32 (compiler-generated; guide m240)
__device__ __forceinline__ u32 pkbf(float lo, float hi) {
  __hip_bfloat162 h = __float22bfloat162_rn(float2{lo, hi});
  u32 r;
  __builtin_memcpy(&r, &h, 4);
  return r;
}

__device__ __forceinline__ void gload_lds16(const void* g, void* l) {
  __builtin_amdgcn_global_load_lds((u32 __attribute__((address_space(1)))*)(g),
                                   (u32 __attribute__((address_space(3)))*)(l),
                                   16, 0, 0);
}

// ---------------- conversions ----------------

__global__ void k_cvt_q(const float* __restrict__ src, u16* __restrict__ dst) {
  const int i = (blockIdx.x * 256 + threadIdx.x) * 4;
  float4 v = *(const float4*)(src + i);
  u32x2 o;
  o[0] = pkbf(v.x, v.y); o[1] = pkbf(v.z, v.w);
  *(u32x2*)(dst + i) = o;
}

// W_query/key/val: [H=16][D=1024][K=64] -> Bt layout [n=h*64+k][d]
__global__ void k_cvt_wproj(const float* __restrict__ w, u16* __restrict__ wt) {
  const int idx = blockIdx.x * 256 + threadIdx.x;
  const int n = idx >> 10, d = idx & 1023;
  wt[idx] = f2bf(w[((n >> 6) << 16) + (d << 6) + (n & 63)]);
}

// W_out: [hv=1024][e=1024] -> Bt layout [e][hv]
__global__ void k_cvt_wout(const float* __restrict__ w, u16* __restrict__ wt) {
  const int idx = blockIdx.x * 256 + threadIdx.x;
  const int e = idx >> 10, hv = idx & 1023;
  wt[idx] = f2bf(w[(hv << 10) + e]);
}

// ---------------- GEMM: C[m][n] = sum_k A[m][k] * Bt[n][k] ----------------
// MODE: 0 = bf16 natural, 1 = f32 natural, 2 = bf16 natural * QSCALE,
// MODE 3 = bf16 transposed [n][MTOT] with PV k-order permutation baked into m:
//          within each 32-run of m (m = 32a+16s+4g+r), store at m' = 32a+8g+4s+r.

#define BM 128
#define BN 128
#define BK 32

template<int MODE>
__device__ __forceinline__ void gemm_tile(const u16* __restrict__ A, const u16* __restrict__ Bt,
                                          void* __restrict__ Cp, int m0, int n0, int K, int N) {
  __shared__ u16 sA[BM * BK];
  __shared__ u16 sB[BN * BK];
  const int tid = threadIdx.x;
  const int wid = tid >> 6, lane = tid & 63;
  const int g = lane >> 4, li = lane & 15;
  const int wr = (wid >> 1) * 64, wc = (wid & 1) * 64;

  f32x4 acc[4][4] = {};

  for (int k0 = 0; k0 < K; k0 += BK) {
    __syncthreads();
#pragma unroll
    for (int c = 0; c < 2; ++c) {
      const int chunk = c * 256 + tid;
      const int row = chunk >> 2;
      const int ke  = (chunk & 3) * 8;
      gload_lds16(A  + (size_t)(m0 + row) * K + k0 + ke, sA + (size_t)(c * 256 + wid * 64) * 8);
      gload_lds16(Bt + (size_t)(n0 + row) * K + k0 + ke, sB + (size_t)(c * 256 + wid * 64) * 8);
    }
    __syncthreads();

    bf16x8 af[4], bfr[4];
#pragma unroll
    for (int t = 0; t < 4; ++t) {
      af[t]  = *(const bf16x8*)(sA + (wr + t * 16 + li) * BK + g * 8);
      bfr[t] = *(const bf16x8*)(sB + (wc + t * 16 + li) * BK + g * 8);
    }
    __builtin_amdgcn_s_setprio(1);
#pragma unroll
    for (int i = 0; i < 4; ++i)
#pragma unroll
      for (int j = 0; j < 4; ++j)
        acc[i][j] = __builtin_amdgcn_mfma_f32_16x16x32_bf16(af[i], bfr[j], acc[i][j], 0, 0, 0);
    __builtin_amdgcn_s_setprio(0);
  }

#pragma unroll
  for (int i = 0; i < 4; ++i)
#pragma unroll
    for (int j = 0; j < 4; ++j) {
      if (MODE == 3) {
        const int col = n0 + wc + j * 16 + li;
        // rowb = 32a + 16(i&1) + 4g ; permuted base = rowb + 4g - 12(i&1)
        const size_t rowb = (size_t)(m0 + wr + i * 16 + g * 4) + 4 * g - 12 * (i & 1);
        u32x2 w;
        w[0] = pkbf(acc[i][j][0], acc[i][j][1]);
        w[1] = pkbf(acc[i][j][2], acc[i][j][3]);
        *(u32x2*)((u16*)Cp + (size_t)col * MTOT + rowb) = w;
      } else if (MODE == 1) {
#pragma unroll
        for (int r = 0; r < 4; ++r) {
          const size_t row = (size_t)(m0 + wr + i * 16 + g * 4 + r);
          ((float*)Cp)[row * N + n0 + wc + j * 16 + li] = acc[i][j][r];
        }
      } else {
#pragma unroll
        for (int r = 0; r < 4; ++r) {
          const size_t row = (size_t)(m0 + wr + i * 16 + g * 4 + r);
          float v = acc[i][j][r];
          if (MODE == 2) v *= QSCALE;
          ((u16*)Cp)[row * N + n0 + wc + j * 16 + li] = f2bf(v);
        }
      }
    }
}

__global__ __launch_bounds__(256)
void k_gemm_qkv(const u16* __restrict__ A,
                const u16* __restrict__ wq, const u16* __restrict__ wk, const u16* __restrict__ wv,
                u16* __restrict__ Qo, u16* __restrict__ Ko, u16* __restrict__ Vto) {
  const int m0 = blockIdx.x * BM;
  const int yt = blockIdx.y;
  const int wsel = yt >> 3;
  const int n0 = (yt & 7) * BN;
  if (wsel == 0)      gemm_tile<2>(A, wq, Qo,  m0, n0, DIM, DIM);   // Q, pre-scaled
  else if (wsel == 1) gemm_tile<0>(A, wk, Ko,  m0, n0, DIM, DIM);   // K natural
  else                gemm_tile<3>(A, wv, Vto, m0, n0, DIM, DIM);   // V^T [n][m'], m-permuted
}

__global__ __launch_bounds__(256)
void k_gemm_out(const u16* __restrict__ A, const u16* __restrict__ Bt, float* __restrict__ C) {
  gemm_tile<1>(A, Bt, C, blockIdx.x * BM, blockIdx.y * BN, DIM, DIM);
}

// ---------------- flash attention ----------------
// grid: (SEQ/128, BATCH*NHEAD); 4 waves, each owns 32 q rows (2 row-tiles).
// Swapped QK^T (S^T = K·Q^T): lane (g,li) holds S[q=li][kv=16t+4g+r] -> softmax lane-local.
// PV as O^T = V^T·P^T; k-order permutation baked into V^T global layout so the
// V fragment is ONE swizzled ds_read_b128 (same pattern as K reads).
// Double-buffered prefetch; defer-max (THR=8); raw v_exp; cvt_pk packing; setprio.

#define KB 64
#define NT (SEQ/KB)

__global__ __launch_bounds__(256, 4)
void k_attn(const u16* __restrict__ Q, const u16* __restrict__ K,
            const u16* __restrict__ Vt, u16* __restrict__ O) {
  const int qt = blockIdx.x, bh = blockIdx.y;
  const int b = bh >> 4, h = bh & 15;
  const int q0 = qt * 128;
  const int tid = threadIdx.x, wid = tid >> 6, lane = tid & 63;
  const int g = lane >> 4, li = lane & 15;

  __shared__ u16 kl[2][KB * 64];    // K tile  [kv][d], swizzled
  __shared__ u16 vl[2][64 * KB];    // V^T tile [dv][kv'], swizzled (kv' pre-permuted)

  const size_t rb = (size_t)b * SEQ;
  const int hc = h * DKV;

  bf16x8 qf[2][2];
#pragma unroll
  for (int u = 0; u < 2; ++u) {
    const u16* qp = Q + (rb + q0 + wid * 32 + u * 16 + li) * DIM + hc;
    qf[u][0] = *(const bf16x8*)(qp + g * 8);
    qf[u][1] = *(const bf16x8*)(qp + 32 + g * 8);
  }

  float mrun[2] = {-1e30f, -1e30f};
  float lrun[2] = {0.f, 0.f};
  f32x4 o[2][4] = {};

  const int r8  = lane >> 3;
  const int swz = ((lane & 7) ^ r8) * 8;

  // prologue: stage tile 0 into buffer 0
#pragma unroll
  for (int c = 0; c < 2; ++c) {
    const int row = (c * 4 + wid) * 8 + r8;
    gload_lds16(K  + (rb + row) * DIM + hc + swz,            &kl[0][(c * 4 + wid) * 512]);
    gload_lds16(Vt + (size_t)(hc + row) * MTOT + rb + swz,   &vl[0][(c * 4 + wid) * 512]);
  }

  for (int it = 0; it < NT; ++it) {
    const int cur = it & 1;
    __syncthreads();

    if (it + 1 < NT) {
      const int n1 = (it + 1) * KB;
#pragma unroll
      for (int c = 0; c < 2; ++c) {
        const int row = (c * 4 + wid) * 8 + r8;
        gload_lds16(K  + (rb + n1 + row) * DIM + hc + swz,          &kl[cur ^ 1][(c * 4 + wid) * 512]);
        gload_lds16(Vt + (size_t)(hc + row) * MTOT + rb + n1 + swz, &vl[cur ^ 1][(c * 4 + wid) * 512]);
      }
    }

    const u16* kb = kl[cur];
    const u16* vb = vl[cur];
    const int sw = (li & 7) << 3;

    // S^T = K·Q^T : lane (g,li) reg r of s[u][t] = S[q=li][kv = 16t+4g+r]
    f32x4 s[2][4];
    __builtin_amdgcn_s_setprio(1);
#pragma unroll
    for (int t = 0; t < 4; ++t) {
      const int row = t * 16 + li;
      bf16x8 kf0 = *(const bf16x8*)(kb + row * 64 + ((g * 8) ^ sw));
      bf16x8 kf1 = *(const bf16x8*)(kb + row * 64 + ((32 + g * 8) ^ sw));
#pragma unroll
      for (int u = 0; u < 2; ++u) {
        f32x4 z = {};
        z = __builtin_amdgcn_mfma_f32_16x16x32_bf16(kf0, qf[u][0], z, 0, 0, 0);
        z = __builtin_amdgcn_mfma_f32_16x16x32_bf16(kf1, qf[u][1], z, 0, 0, 0);
        s[u][t] = z;
      }
    }
    __builtin_amdgcn_s_setprio(0);

    // online softmax (exp2 domain), defer-max, vectorized reductions, cvt_pk pack
    bf16x8 pa[2][2];
#pragma unroll
    for (int u = 0; u < 2; ++u) {
      f32x4 mv = __builtin_elementwise_max(__builtin_elementwise_max(s[u][0], s[u][1]),
                                           __builtin_elementwise_max(s[u][2], s[u][3]));
      float pmax = fmaxf(fmaxf(mv[0], mv[1]), fmaxf(mv[2], mv[3]));
      pmax = fmaxf(pmax, __shfl_xor(pmax, 16));
      pmax = fmaxf(pmax, __shfl_xor(pmax, 32));
      if (__any(pmax - mrun[u] > THR)) {     // T13 defer-max: rescale only when needed
        const float mn = fmaxf(mrun[u], pmax);
        const float corr = __builtin_amdgcn_exp2f(mrun[u] - mn);
        mrun[u] = mn;
        lrun[u] *= corr;
#pragma unroll
        for (int t = 0; t < 4; ++t) o[u][t] *= corr;
      }
      const float mb = mrun[u];
#pragma unroll
      for (int t = 0; t < 4; ++t)
#pragma unroll
        for (int r = 0; r < 4; ++r)
          s[u][t][r] = __builtin_amdgcn_exp2f(s[u][t][r] - mb);   // raw v_exp_f32
      f32x4 sv = (s[u][0] + s[u][1]) + (s[u][2] + s[u][3]);
      float ps = (sv[0] + sv[1]) + (sv[2] + sv[3]);
      ps += __shfl_xor(ps, 16);
      ps += __shfl_xor(ps, 32);
      lrun[u] += ps;
      // pack: pa word j of half hh = p[t=2hh+(j>>2)][r=j&3]; pairs adjacent -> cvt_pk
#pragma unroll
      for (int hh = 0; hh < 2; ++hh) {
        u32x4 pw;
        pw[0] = pkbf(s[u][2 * hh][0],     s[u][2 * hh][1]);
        pw[1] = pkbf(s[u][2 * hh][2],     s[u][2 * hh][3]);
        pw[2] = pkbf(s[u][2 * hh + 1][0], s[u][2 * hh + 1][1]);
        pw[3] = pkbf(s[u][2 * hh + 1][2], s[u][2 * hh + 1][3]);
        pa[u][hh] = __builtin_bit_cast(bf16x8, pw);
      }
    }

    // O^T += V^T · P^T : V fragment is one swizzled b128 (layout pre-permuted)
    __builtin_amdgcn_s_setprio(1);
#pragma unroll
    for (int t = 0; t < 4; ++t) {
      const int row = t * 16 + li;
#pragma unroll
      for (int hh = 0; hh < 2; ++hh) {
        bf16x8 vf = *(const bf16x8*)(vb + row * 64 + ((hh * 32 + g * 8) ^ sw));
#pragma unroll
        for (int u = 0; u < 2; ++u)
          o[u][t] = __builtin_amdgcn_mfma_f32_16x16x32_bf16(vf, pa[u][hh], o[u][t], 0, 0, 0);
      }
    }
    __builtin_amdgcn_s_setprio(0);
  }

  // epilogue: lane (g,li) holds O[q=li][dv = 16t+4g+r]
#pragma unroll
  for (int u = 0; u < 2; ++u) {
    const float inv = 1.0f / lrun[u];
    const size_t qrow = rb + q0 + wid * 32 + u * 16 + li;
#pragma unroll
    for (int t = 0; t < 4; ++t) {
      u32x2 w;
      w[0] = pkbf(o[u][t][0] * inv, o[u][t][1] * inv);
      w[1] = pkbf(o[u][t][2] * inv, o[u][t][3] * inv);
      *(u32x2*)(O + qrow * DIM + hc + t * 16 + 4 * g) = w;
    }
  }
}

// ---------------- launch ----------------

extern "C" void kernel_launch(void* const* d_in, const int* in_sizes, int n_in,
                              void* d_out, int out_size, void* d_ws, size_t ws_size,
                              hipStream_t stream) {
  (void)in_sizes; (void)n_in; (void)out_size; (void)ws_size;
  const float* q  = (const float*)d_in[0];
  const float* Wq = (const float*)d_in[1];
  const float* Wk = (const float*)d_in[2];
  const float* Wv = (const float*)d_in[3];
  const float* Wo = (const float*)d_in[4];
  float* out = (float*)d_out;

  char* p = (char*)d_ws;
  u16* qb  = (u16*)p; p += (size_t)MTOT * DIM * 2;   // 16MB
  u16* wqt = (u16*)p; p += (size_t)DIM * DIM * 2;    // 2MB
  u16* wkt = (u16*)p; p += (size_t)DIM * DIM * 2;
  u16* wvt = (u16*)p; p += (size_t)DIM * DIM * 2;
  u16* wot = (u16*)p; p += (size_t)DIM * DIM * 2;
  u16* Qb  = (u16*)p; p += (size_t)MTOT * DIM * 2;   // 16MB (pre-scaled Q)
  u16* Kb  = (u16*)p; p += (size_t)MTOT * DIM * 2;   // 16MB
  u16* Vtb = (u16*)p; p += (size_t)MTOT * DIM * 2;   // 16MB, [n=h*64+dv][m'], m-permuted
  u16* Hb  = Qb;  // heads reuse Q buffer (attn reads its Q tile to regs before writing same region)

  k_cvt_q<<<(MTOT * DIM / 4) / 256, 256, 0, stream>>>(q, qb);
  k_cvt_wproj<<<(DIM * DIM) / 256, 256, 0, stream>>>(Wq, wqt);
  k_cvt_wproj<<<(DIM * DIM) / 256, 256, 0, stream>>>(Wk, wkt);
  k_cvt_wproj<<<(DIM * DIM) / 256, 256, 0, stream>>>(Wv, wvt);
  k_cvt_wout<<<(DIM * DIM) / 256, 256, 0, stream>>>(Wo, wot);

  k_gemm_qkv<<<dim3(MTOT / BM, 24), 256, 0, stream>>>(qb, wqt, wkt, wvt, Qb, Kb, Vtb);
  k_attn<<<dim3(SEQ / 128, BATCH * NHEAD), 256, 0, stream>>>(Qb, Kb, Vtb, Hb);
  k_gemm_out<<<dim3(MTOT / BM, DIM / BN), 256, 0, stream>>>(Hb, wot, out);
}

// Round 6
// 245.307 us; speedup vs baseline: 1.7052x; 1.0124x over previous
//
#include <hip/hip_runtime.h>
#include <hip/hip_bf16.h>
#include <stdint.h>
#include <math.h>

#define BATCH 4
#define SEQ   2048
#define NHEAD 16
#define DIM   1024
#define DKV   64
#define MTOT  (BATCH*SEQ)   // 8192

typedef __attribute__((ext_vector_type(8))) short  bf16x8;
typedef __attribute__((ext_vector_type(4))) float  f32x4;
typedef unsigned short u16;
typedef unsigned int   u32;
typedef __attribute__((ext_vector_type(4))) u16 u16x4;
typedef __attribute__((ext_vector_type(2))) u32 u32x2;
typedef __attribute__((ext_vector_type(4))) u32 u32x4;

// 0.125 (1/sqrt(dk)) * log2(e): folded into Q so attention runs exp2-domain.
#define QSCALE 0.18033688011112042f
#define THR    8.0f

__device__ __forceinline__ u16 f2bf(float f) {
  __hip_bfloat16 h = __float2bfloat16(f);
  u16 r;
  __builtin_memcpy(&r, &h, 2);
  return r;
}
// packed pair -> one v_cvt_pk_bf16_f32 (compiler-generated; guide m240)
__device__ __forceinline__ u32 pkbf(float lo, float hi) {
  __hip_bfloat162 h = __float22bfloat162_rn(float2{lo, hi});
  u32 r;
  __builtin_memcpy(&r, &h, 4);
  return r;
}

__device__ __forceinline__ void gload_lds16(const void* g, void* l) {
  __builtin_amdgcn_global_load_lds((u32 __attribute__((address_space(1)))*)(g),
                                   (u32 __attribute__((address_space(3)))*)(l),
                                   16, 0, 0);
}

// ---------------- conversions ----------------

__global__ void k_cvt_q(const float* __restrict__ src, u16* __restrict__ dst) {
  const int i = (blockIdx.x * 256 + threadIdx.x) * 4;
  float4 v = *(const float4*)(src + i);
  u32x2 o;
  o[0] = pkbf(v.x, v.y); o[1] = pkbf(v.z, v.w);
  *(u32x2*)(dst + i) = o;
}

// W_query/key/val: [H=16][D=1024][K=64] -> Bt layout [n=h*64+k][d]
__global__ void k_cvt_wproj(const float* __restrict__ w, u16* __restrict__ wt) {
  const int idx = blockIdx.x * 256 + threadIdx.x;
  const int n = idx >> 10, d = idx & 1023;
  wt[idx] = f2bf(w[((n >> 6) << 16) + (d << 6) + (n & 63)]);
}

// W_out: [hv=1024][e=1024] -> Bt layout [e][hv]
__global__ void k_cvt_wout(const float* __restrict__ w, u16* __restrict__ wt) {
  const int idx = blockIdx.x * 256 + threadIdx.x;
  const int e = idx >> 10, hv = idx & 1023;
  wt[idx] = f2bf(w[(hv << 10) + e]);
}

// ---------------- GEMM: C[m][n] = sum_k A[m][k] * Bt[n][k] ----------------
// MODE: 0 = bf16 natural, 1 = f32 natural, 2 = bf16 natural * QSCALE,
// MODE 3 = bf16 transposed [n][MTOT] with PV k-order permutation baked into m:
//          within each 32-run of m (m = 32a+16s+4g+r), store at m' = 32a+8g+4s+r.

#define BM 128
#define BN 128
#define BK 32

template<int MODE>
__device__ __forceinline__ void gemm_tile(const u16* __restrict__ A, const u16* __restrict__ Bt,
                                          void* __restrict__ Cp, int m0, int n0, int K, int N) {
  __shared__ u16 sA[BM * BK];
  __shared__ u16 sB[BN * BK];
  const int tid = threadIdx.x;
  const int wid = tid >> 6, lane = tid & 63;
  const int g = lane >> 4, li = lane & 15;
  const int wr = (wid >> 1) * 64, wc = (wid & 1) * 64;

  f32x4 acc[4][4] = {};

  for (int k0 = 0; k0 < K; k0 += BK) {
    __syncthreads();
#pragma unroll
    for (int c = 0; c < 2; ++c) {
      const int chunk = c * 256 + tid;
      const int row = chunk >> 2;
      const int ke  = (chunk & 3) * 8;
      gload_lds16(A  + (size_t)(m0 + row) * K + k0 + ke, sA + (size_t)(c * 256 + wid * 64) * 8);
      gload_lds16(Bt + (size_t)(n0 + row) * K + k0 + ke, sB + (size_t)(c * 256 + wid * 64) * 8);
    }
    __syncthreads();

    bf16x8 af[4], bfr[4];
#pragma unroll
    for (int t = 0; t < 4; ++t) {
      af[t]  = *(const bf16x8*)(sA + (wr + t * 16 + li) * BK + g * 8);
      bfr[t] = *(const bf16x8*)(sB + (wc + t * 16 + li) * BK + g * 8);
    }
    __builtin_amdgcn_s_setprio(1);
#pragma unroll
    for (int i = 0; i < 4; ++i)
#pragma unroll
      for (int j = 0; j < 4; ++j)
        acc[i][j] = __builtin_amdgcn_mfma_f32_16x16x32_bf16(af[i], bfr[j], acc[i][j], 0, 0, 0);
    __builtin_amdgcn_s_setprio(0);
  }

#pragma unroll
  for (int i = 0; i < 4; ++i)
#pragma unroll
    for (int j = 0; j < 4; ++j) {
      if (MODE == 3) {
        const int col = n0 + wc + j * 16 + li;
        // rowb = 32a + 16(i&1) + 4g ; permuted base = rowb + 4g - 12(i&1)
        const size_t rowb = (size_t)(m0 + wr + i * 16 + g * 4) + 4 * g - 12 * (i & 1);
        u32x2 w;
        w[0] = pkbf(acc[i][j][0], acc[i][j][1]);
        w[1] = pkbf(acc[i][j][2], acc[i][j][3]);
        *(u32x2*)((u16*)Cp + (size_t)col * MTOT + rowb) = w;
      } else if (MODE == 1) {
#pragma unroll
        for (int r = 0; r < 4; ++r) {
          const size_t row = (size_t)(m0 + wr + i * 16 + g * 4 + r);
          ((float*)Cp)[row * N + n0 + wc + j * 16 + li] = acc[i][j][r];
        }
      } else {
#pragma unroll
        for (int r = 0; r < 4; ++r) {
          const size_t row = (size_t)(m0 + wr + i * 16 + g * 4 + r);
          float v = acc[i][j][r];
          if (MODE == 2) v *= QSCALE;
          ((u16*)Cp)[row * N + n0 + wc + j * 16 + li] = f2bf(v);
        }
      }
    }
}

__global__ __launch_bounds__(256)
void k_gemm_qkv(const u16* __restrict__ A,
                const u16* __restrict__ wq, const u16* __restrict__ wk, const u16* __restrict__ wv,
                u16* __restrict__ Qo, u16* __restrict__ Ko, u16* __restrict__ Vto) {
  const int m0 = blockIdx.x * BM;
  const int yt = blockIdx.y;
  const int wsel = yt >> 3;
  const int n0 = (yt & 7) * BN;
  if (wsel == 0)      gemm_tile<2>(A, wq, Qo,  m0, n0, DIM, DIM);   // Q, pre-scaled
  else if (wsel == 1) gemm_tile<0>(A, wk, Ko,  m0, n0, DIM, DIM);   // K natural
  else                gemm_tile<3>(A, wv, Vto, m0, n0, DIM, DIM);   // V^T [n][m'], m-permuted
}

__global__ __launch_bounds__(256)
void k_gemm_out(const u16* __restrict__ A, const u16* __restrict__ Bt, float* __restrict__ C) {
  gemm_tile<1>(A, Bt, C, blockIdx.x * BM, blockIdx.y * BN, DIM, DIM);
}

// ---------------- flash attention ----------------
// grid: (SEQ/128, BATCH*NHEAD), 512 threads = 8 waves, each wave owns 16 q rows.
// Swapped QK^T (S^T = K·Q^T): lane (g,li) holds S[q=li][kv=16t+4g+r] -> softmax lane-local.
// PV as O^T = V^T·P^T; k-order permutation baked into V^T global layout.
// Row-sum of P via ones-MFMA (contracts across lanes; no shfl). Defer-max with
// cheap __any check. Double-buffered gload_lds prefetch; raw v_exp; cvt_pk; setprio.

#define KB 64
#define NT (SEQ/KB)

__global__ __launch_bounds__(512, 8)
void k_attn(const u16* __restrict__ Q, const u16* __restrict__ K,
            const u16* __restrict__ Vt, u16* __restrict__ O) {
  const int qt = blockIdx.x, bh = blockIdx.y;
  const int b = bh >> 4, h = bh & 15;
  const int q0 = qt * 128;
  const int tid = threadIdx.x, wid = tid >> 6, lane = tid & 63;
  const int g = lane >> 4, li = lane & 15;

  __shared__ u16 kl[2][KB * 64];    // K tile  [kv][d], swizzled      (8KB each)
  __shared__ u16 vl[2][KB * 64];    // V^T tile [dv][kv'], swizzled   (8KB each)

  const size_t rb = (size_t)b * SEQ;
  const int hc = h * DKV;

  // Q fragments (B-operand): rows q0 + wid*16 + li
  bf16x8 qf0, qf1;
  {
    const u16* qp = Q + (rb + q0 + wid * 16 + li) * DIM + hc;
    qf0 = *(const bf16x8*)(qp + g * 8);
    qf1 = *(const bf16x8*)(qp + 32 + g * 8);
  }

  bf16x8 ones;
#pragma unroll
  for (int j = 0; j < 8; ++j) ones[j] = (short)0x3F80;   // bf16 1.0

  float mrun = -1e30f, lrun = 0.f;
  f32x4 o[4] = {};

  const int r8   = lane >> 3;
  const int swz  = ((lane & 7) ^ r8) * 8;   // pre-swizzled source element offset
  const int srow = wid * 8 + r8;            // staging row owned by this lane

  // prologue: stage tile 0 into buffer 0 (512 threads cover 64x64 in one shot)
  gload_lds16(K  + (rb + srow) * DIM + hc + swz,          &kl[0][wid * 512]);
  gload_lds16(Vt + (size_t)(hc + srow) * MTOT + rb + swz, &vl[0][wid * 512]);

  for (int it = 0; it < NT; ++it) {
    const int cur = it & 1;
    __syncthreads();   // implicit vmcnt drain: buf[cur] staged; prev readers done

    if (it + 1 < NT) {
      const int n1 = (it + 1) * KB;
      gload_lds16(K  + (rb + n1 + srow) * DIM + hc + swz,          &kl[cur ^ 1][wid * 512]);
      gload_lds16(Vt + (size_t)(hc + srow) * MTOT + rb + n1 + swz, &vl[cur ^ 1][wid * 512]);
    }

    const u16* kb = kl[cur];
    const u16* vb = vl[cur];
    const int sw = (li & 7) << 3;

    // S^T = K·Q^T : lane (g,li) reg r of s[t] = S[q=li][kv = 16t+4g+r]
    f32x4 s[4];
    __builtin_amdgcn_s_setprio(1);
#pragma unroll
    for (int t = 0; t < 4; ++t) {
      const int row = t * 16 + li;
      bf16x8 kf0 = *(const bf16x8*)(kb + row * 64 + ((g * 8) ^ sw));
      bf16x8 kf1 = *(const bf16x8*)(kb + row * 64 + ((32 + g * 8) ^ sw));
      f32x4 z = {};
      z = __builtin_amdgcn_mfma_f32_16x16x32_bf16(kf0, qf0, z, 0, 0, 0);
      z = __builtin_amdgcn_mfma_f32_16x16x32_bf16(kf1, qf1, z, 0, 0, 0);
      s[t] = z;
    }
    __builtin_amdgcn_s_setprio(0);

    // defer-max: cheap lane-local check; full reduce only when triggered (rare)
    f32x4 mv = __builtin_elementwise_max(__builtin_elementwise_max(s[0], s[1]),
                                         __builtin_elementwise_max(s[2], s[3]));
    const float lmax = fmaxf(fmaxf(mv[0], mv[1]), fmaxf(mv[2], mv[3]));
    if (__any(lmax - mrun > THR)) {
      float pmax = fmaxf(lmax, __shfl_xor(lmax, 16));
      pmax = fmaxf(pmax, __shfl_xor(pmax, 32));
      const float mn = fmaxf(mrun, pmax);
      const float corr = __builtin_amdgcn_exp2f(mrun - mn);
      mrun = mn;
      lrun *= corr;
#pragma unroll
      for (int t = 0; t < 4; ++t) o[t] *= corr;
    }
    const float mb = mrun;
#pragma unroll
    for (int t = 0; t < 4; ++t)
#pragma unroll
      for (int r = 0; r < 4; ++r)
        s[t][r] = __builtin_amdgcn_exp2f(s[t][r] - mb);   // raw v_exp_f32

    // pack: pa word j of half hh = p[t=2hh+(j>>2)][r=j&3]; pairs adjacent -> cvt_pk
    bf16x8 pa[2];
#pragma unroll
    for (int hh = 0; hh < 2; ++hh) {
      u32x4 pw;
      pw[0] = pkbf(s[2 * hh][0],     s[2 * hh][1]);
      pw[1] = pkbf(s[2 * hh][2],     s[2 * hh][3]);
      pw[2] = pkbf(s[2 * hh + 1][0], s[2 * hh + 1][1]);
      pw[3] = pkbf(s[2 * hh + 1][2], s[2 * hh + 1][3]);
      pa[hh] = __builtin_bit_cast(bf16x8, pw);
    }

    // row-sum of P via ones-MFMA: contracts over K=32 incl. cross-lane groups;
    // every reg/lane with the same q=li gets the full 64-wide sum.
    f32x4 zs = {};
    zs = __builtin_amdgcn_mfma_f32_16x16x32_bf16(ones, pa[0], zs, 0, 0, 0);
    zs = __builtin_amdgcn_mfma_f32_16x16x32_bf16(ones, pa[1], zs, 0, 0, 0);

    // O^T += V^T · P^T : V fragment is one swizzled b128 (layout pre-permuted)
    __builtin_amdgcn_s_setprio(1);
#pragma unroll
    for (int t = 0; t < 4; ++t) {
      const int row = t * 16 + li;
#pragma unroll
      for (int hh = 0; hh < 2; ++hh) {
        bf16x8 vf = *(const bf16x8*)(vb + row * 64 + ((hh * 32 + g * 8) ^ sw));
        o[t] = __builtin_amdgcn_mfma_f32_16x16x32_bf16(vf, pa[hh], o[t], 0, 0, 0);
      }
    }
    __builtin_amdgcn_s_setprio(0);

    lrun += zs[0];
  }

  // epilogue: lane (g,li) holds O[q=li][dv = 16t+4g+r]
  {
    const float inv = 1.0f / lrun;
    const size_t qrow = rb + q0 + wid * 16 + li;
#pragma unroll
    for (int t = 0; t < 4; ++t) {
      u32x2 w;
      w[0] = pkbf(o[t][0] * inv, o[t][1] * inv);
      w[1] = pkbf(o[t][2] * inv, o[t][3] * inv);
      *(u32x2*)(O + qrow * DIM + hc + t * 16 + 4 * g) = w;
    }
  }
}

// ---------------- launch ----------------

extern "C" void kernel_launch(void* const* d_in, const int* in_sizes, int n_in,
                              void* d_out, int out_size, void* d_ws, size_t ws_size,
                              hipStream_t stream) {
  (void)in_sizes; (void)n_in; (void)out_size; (void)ws_size;
  const float* q  = (const float*)d_in[0];
  const float* Wq = (const float*)d_in[1];
  const float* Wk = (const float*)d_in[2];
  const float* Wv = (const float*)d_in[3];
  const float* Wo = (const float*)d_in[4];
  float* out = (float*)d_out;

  char* p = (char*)d_ws;
  u16* qb  = (u16*)p; p += (size_t)MTOT * DIM * 2;   // 16MB
  u16* wqt = (u16*)p; p += (size_t)DIM * DIM * 2;    // 2MB
  u16* wkt = (u16*)p; p += (size_t)DIM * DIM * 2;
  u16* wvt = (u16*)p; p += (size_t)DIM * DIM * 2;
  u16* wot = (u16*)p; p += (size_t)DIM * DIM * 2;
  u16* Qb  = (u16*)p; p += (size_t)MTOT * DIM * 2;   // 16MB (pre-scaled Q)
  u16* Kb  = (u16*)p; p += (size_t)MTOT * DIM * 2;   // 16MB
  u16* Vtb = (u16*)p; p += (size_t)MTOT * DIM * 2;   // 16MB, [n=h*64+dv][m'], m-permuted
  u16* Hb  = Qb;  // heads reuse Q buffer (attn reads its Q tile to regs before writing same region)

  k_cvt_q<<<(MTOT * DIM / 4) / 256, 256, 0, stream>>>(q, qb);
  k_cvt_wproj<<<(DIM * DIM) / 256, 256, 0, stream>>>(Wq, wqt);
  k_cvt_wproj<<<(DIM * DIM) / 256, 256, 0, stream>>>(Wk, wkt);
  k_cvt_wproj<<<(DIM * DIM) / 256, 256, 0, stream>>>(Wv, wvt);
  k_cvt_wout<<<(DIM * DIM) / 256, 256, 0, stream>>>(Wo, wot);

  k_gemm_qkv<<<dim3(MTOT / BM, 24), 256, 0, stream>>>(qb, wqt, wkt, wvt, Qb, Kb, Vtb);
  k_attn<<<dim3(SEQ / 128, BATCH * NHEAD), 512, 0, stream>>>(Qb, Kb, Vtb, Hb);
  k_gemm_out<<<dim3(MTOT / BM, DIM / BN), 256, 0, stream>>>(Hb, wot, out);
}

// Round 7
// 220.406 us; speedup vs baseline: 1.8978x; 1.1130x over previous
//
#include <hip/hip_runtime.h>
#include <hip/hip_bf16.h>
#include <stdint.h>
#include <math.h>

#define BATCH 4
#define SEQ   2048
#define NHEAD 16
#define DIM   1024
#define DKV   64
#define MTOT  (BATCH*SEQ)   // 8192

typedef __attribute__((ext_vector_type(8))) short  bf16x8;
typedef __attribute__((ext_vector_type(4))) float  f32x4;
typedef unsigned short u16;
typedef unsigned int   u32;
typedef __attribute__((ext_vector_type(4))) u16 u16x4;
typedef __attribute__((ext_vector_type(2))) u32 u32x2;
typedef __attribute__((ext_vector_type(4))) u32 u32x4;

// 0.125 (1/sqrt(dk)) * log2(e): folded into Q so attention runs exp2-domain.
#define QSCALE 0.18033688011112042f
#define THR    8.0f

__device__ __forceinline__ u16 f2bf(float f) {
  __hip_bfloat16 h = __float2bfloat16(f);
  u16 r;
  __builtin_memcpy(&r, &h, 2);
  return r;
}
__device__ __forceinline__ u32 pkbf(float lo, float hi) {
  __hip_bfloat162 h = __float22bfloat162_rn(float2{lo, hi});
  u32 r;
  __builtin_memcpy(&r, &h, 4);
  return r;
}

__device__ __forceinline__ void gload_lds16(const void* g, void* l) {
  __builtin_amdgcn_global_load_lds((u32 __attribute__((address_space(1)))*)(g),
                                   (u32 __attribute__((address_space(3)))*)(l),
                                   16, 0, 0);
}

// ---------------- conversions ----------------

__global__ void k_cvt_q(const float* __restrict__ src, u16* __restrict__ dst) {
  const int i = (blockIdx.x * 256 + threadIdx.x) * 4;
  float4 v = *(const float4*)(src + i);
  u32x2 o;
  o[0] = pkbf(v.x, v.y); o[1] = pkbf(v.z, v.w);
  *(u32x2*)(dst + i) = o;
}

__global__ void k_cvt_wproj(const float* __restrict__ w, u16* __restrict__ wt) {
  const int idx = blockIdx.x * 256 + threadIdx.x;
  const int n = idx >> 10, d = idx & 1023;
  wt[idx] = f2bf(w[((n >> 6) << 16) + (d << 6) + (n & 63)]);
}

__global__ void k_cvt_wout(const float* __restrict__ w, u16* __restrict__ wt) {
  const int idx = blockIdx.x * 256 + threadIdx.x;
  const int e = idx >> 10, hv = idx & 1023;
  wt[idx] = f2bf(w[(hv << 10) + e]);
}

// ---------------- legacy 128x128 GEMM (kept for out-proj) ----------------

#define BM 128
#define BN 128
#define BK 32

__global__ __launch_bounds__(256)
void k_gemm_out(const u16* __restrict__ A, const u16* __restrict__ Bt, float* __restrict__ C) {
  __shared__ u16 sA[BM * BK];
  __shared__ u16 sB[BN * BK];
  const int m0 = blockIdx.x * BM, n0 = blockIdx.y * BN;
  const int tid = threadIdx.x;
  const int wid = tid >> 6, lane = tid & 63;
  const int g = lane >> 4, li = lane & 15;
  const int wr = (wid >> 1) * 64, wc = (wid & 1) * 64;

  f32x4 acc[4][4] = {};

  for (int k0 = 0; k0 < DIM; k0 += BK) {
    __syncthreads();
#pragma unroll
    for (int c = 0; c < 2; ++c) {
      const int chunk = c * 256 + tid;
      const int row = chunk >> 2;
      const int ke  = (chunk & 3) * 8;
      gload_lds16(A  + (size_t)(m0 + row) * DIM + k0 + ke, sA + (size_t)(c * 256 + wid * 64) * 8);
      gload_lds16(Bt + (size_t)(n0 + row) * DIM + k0 + ke, sB + (size_t)(c * 256 + wid * 64) * 8);
    }
    __syncthreads();

    bf16x8 af[4], bfr[4];
#pragma unroll
    for (int t = 0; t < 4; ++t) {
      af[t]  = *(const bf16x8*)(sA + (wr + t * 16 + li) * BK + g * 8);
      bfr[t] = *(const bf16x8*)(sB + (wc + t * 16 + li) * BK + g * 8);
    }
    __builtin_amdgcn_s_setprio(1);
#pragma unroll
    for (int i = 0; i < 4; ++i)
#pragma unroll
      for (int j = 0; j < 4; ++j)
        acc[i][j] = __builtin_amdgcn_mfma_f32_16x16x32_bf16(af[i], bfr[j], acc[i][j], 0, 0, 0);
    __builtin_amdgcn_s_setprio(0);
  }

#pragma unroll
  for (int i = 0; i < 4; ++i)
#pragma unroll
    for (int j = 0; j < 4; ++j)
#pragma unroll
      for (int r = 0; r < 4; ++r) {
        const size_t row = (size_t)(m0 + wr + i * 16 + g * 4 + r);
        C[row * DIM + n0 + wc + j * 16 + li] = acc[i][j][r];
      }
}

// ---------------- pipelined 256x256 QKV GEMM (8-phase, counted vmcnt) ----------------
// BM=BN=256, BK=64, 8 waves (2M x 4N), per-wave C = 128x64 (M_rep=8, N_rep=4).
// LDS 128KB: A,B each [2 buf][2 k-half][256 rows][32 k] bf16 (16KB half-tiles).
// Swizzle: lin_elem ^= ((row>>1)&7)<<3  (2-way bank aliasing = free), applied as
// inverse-swizzled per-lane global source + swizzled ds_read (linear gload_lds dest).
// Schedule per K-tile kt (cur=kt&1): 4 phases (ks x m-quadrant);
//  ph1 stages (kt+1).h1-A -> buf[cur^1], ph2 stages (kt+1).h1-B,
//  ph3 stages (kt+2).h0-A -> buf[cur] (region dead after ph2), ph4 stages (kt+2).h0-B.
// Waits: vmcnt(8) at end of ph2 and ph4 only (ledger: newest 8 loads are the
// not-yet-needed half-tiles). Raw s_barrier (no implicit vmcnt(0) drain).

__global__ __launch_bounds__(512, 2)
void k_gemm_qkv8(const u16* __restrict__ A, const u16* __restrict__ wq,
                 const u16* __restrict__ wk, const u16* __restrict__ wv,
                 u16* __restrict__ Qo, u16* __restrict__ Ko, u16* __restrict__ Vto) {
  __shared__ u16 sm[65536];   // A: [0,32768) elems, B: [32768,65536)
  const int tid = threadIdx.x, wid = tid >> 6, lane = tid & 63;
  const int g = lane >> 4, li = lane & 15;
  const int wm = wid >> 2, wn = wid & 3;
  const int m0 = blockIdx.x * 256;
  const int yt = blockIdx.y;
  const int wsel = yt >> 2;
  const int n0 = (yt & 3) * 256;
  const u16* Bt = (wsel == 0) ? wq : (wsel == 1) ? wk : wv;

  // staging: chunk c = (wid*2+p)*64 + lane covers dest elems [c*8, c*8+8) of a half.
  // source lin = (c*8) ^ (((c>>3)&7)<<3)  ->  row = lin>>5, k = lin&31.
  const int c0 = wid * 128 + lane, c1 = c0 + 64;
  const int s0 = (c0 * 8) ^ (((c0 >> 3) & 7) << 3);
  const int s1 = (c1 * 8) ^ (((c1 >> 3) & 7) << 3);
  const u16* As0 = A  + (size_t)(m0 + (s0 >> 5)) * DIM + (s0 & 31);
  const u16* As1 = A  + (size_t)(m0 + (s1 >> 5)) * DIM + (s1 & 31);
  const u16* Bs0 = Bt + (size_t)(n0 + (s0 >> 5)) * DIM + (s0 & 31);
  const u16* Bs1 = Bt + (size_t)(n0 + (s1 >> 5)) * DIM + (s1 & 31);
  u16* dA0 = sm + wid * 1024;        // (wid*2+0)*512
  u16* dA1 = sm + wid * 1024 + 512;
  u16* dB0 = dA0 + 32768;
  u16* dB1 = dA1 + 32768;

#define SA(t, ks, tb) do { \
    gload_lds16(As0 + (t) * 64 + (ks) * 32, dA0 + (tb) * 16384 + (ks) * 8192); \
    gload_lds16(As1 + (t) * 64 + (ks) * 32, dA1 + (tb) * 16384 + (ks) * 8192); } while (0)
#define SB(t, ks, tb) do { \
    gload_lds16(Bs0 + (t) * 64 + (ks) * 32, dB0 + (tb) * 16384 + (ks) * 8192); \
    gload_lds16(Bs1 + (t) * 64 + (ks) * 32, dB1 + (tb) * 16384 + (ks) * 8192); } while (0)

  // read bases: frag addr = base + cur*16384 + ks*8192 + idx*512 (idx = m-rep or n-rep)
  const int vx = ((li >> 1) & 7) << 3;
  const int a_rd = (((wm * 128 + li) * 32) + g * 8) ^ vx;
  const int b_rd = ((((wn * 64 + li) * 32) + g * 8) ^ vx) + 32768;

  f32x4 acc[8][4] = {};

  // prologue: 0.h0, 0.h1, 1.h0  (12 loads); wait for 0.h0
  SA(0, 0, 0); SB(0, 0, 0);
  SA(0, 1, 0); SB(0, 1, 0);
  SA(1, 0, 1); SB(1, 0, 1);
  asm volatile("s_waitcnt vmcnt(8)" ::: "memory");
  __builtin_amdgcn_s_barrier();

#pragma unroll 2
  for (int kt = 0; kt < 16; ++kt) {
    const int cur = kt & 1, t1 = (kt + 1) & 15, t2 = (kt + 2) & 15;
    const u16* pa = sm + cur * 16384 + a_rd;
    const u16* pb = sm + cur * 16384 + b_rd;
    bf16x8 af[4], bfq[4];

    // ---- phase 1: ks0, m-reps 0-3 (8 ds_read)
#pragma unroll
    for (int j = 0; j < 4; ++j) bfq[j] = *(const bf16x8*)(pb + j * 512);
#pragma unroll
    for (int i = 0; i < 4; ++i) af[i] = *(const bf16x8*)(pa + i * 512);
    SA(t1, 1, cur ^ 1);
    __builtin_amdgcn_s_barrier();
    __builtin_amdgcn_s_setprio(1);
#pragma unroll
    for (int i = 0; i < 4; ++i)
#pragma unroll
      for (int j = 0; j < 4; ++j)
        acc[i][j] = __builtin_amdgcn_mfma_f32_16x16x32_bf16(af[i], bfq[j], acc[i][j], 0, 0, 0);
    __builtin_amdgcn_s_setprio(0);
    __builtin_amdgcn_s_barrier();

    // ---- phase 2: ks0, m-reps 4-7 (4 ds_read; B reused)
#pragma unroll
    for (int i = 0; i < 4; ++i) af[i] = *(const bf16x8*)(pa + (i + 4) * 512);
    SB(t1, 1, cur ^ 1);
    __builtin_amdgcn_s_barrier();
    __builtin_amdgcn_s_setprio(1);
#pragma unroll
    for (int i = 0; i < 4; ++i)
#pragma unroll
      for (int j = 0; j < 4; ++j)
        acc[i + 4][j] = __builtin_amdgcn_mfma_f32_16x16x32_bf16(af[i], bfq[j], acc[i + 4][j], 0, 0, 0);
    __builtin_amdgcn_s_setprio(0);
    asm volatile("s_waitcnt vmcnt(8)" ::: "memory");
    __builtin_amdgcn_s_barrier();

    // ---- phase 3: ks1, m-reps 0-3
#pragma unroll
    for (int j = 0; j < 4; ++j) bfq[j] = *(const bf16x8*)(pb + 8192 + j * 512);
#pragma unroll
    for (int i = 0; i < 4; ++i) af[i] = *(const bf16x8*)(pa + 8192 + i * 512);
    SA(t2, 0, cur);
    __builtin_amdgcn_s_barrier();
    __builtin_amdgcn_s_setprio(1);
#pragma unroll
    for (int i = 0; i < 4; ++i)
#pragma unroll
      for (int j = 0; j < 4; ++j)
        acc[i][j] = __builtin_amdgcn_mfma_f32_16x16x32_bf16(af[i], bfq[j], acc[i][j], 0, 0, 0);
    __builtin_amdgcn_s_setprio(0);
    __builtin_amdgcn_s_barrier();

    // ---- phase 4: ks1, m-reps 4-7
#pragma unroll
    for (int i = 0; i < 4; ++i) af[i] = *(const bf16x8*)(pa + 8192 + (i + 4) * 512);
    SB(t2, 0, cur);
    __builtin_amdgcn_s_barrier();
    __builtin_amdgcn_s_setprio(1);
#pragma unroll
    for (int i = 0; i < 4; ++i)
#pragma unroll
      for (int j = 0; j < 4; ++j)
        acc[i + 4][j] = __builtin_amdgcn_mfma_f32_16x16x32_bf16(af[i], bfq[j], acc[i + 4][j], 0, 0, 0);
    __builtin_amdgcn_s_setprio(0);
    asm volatile("s_waitcnt vmcnt(8)" ::: "memory");
    __builtin_amdgcn_s_barrier();
  }
#undef SA
#undef SB

  // epilogue
  if (wsel < 2) {
    u16* C = (wsel == 0) ? Qo : Ko;
    const float qs = (wsel == 0) ? QSCALE : 1.0f;
#pragma unroll
    for (int i = 0; i < 8; ++i)
#pragma unroll
      for (int j = 0; j < 4; ++j) {
        const size_t row = (size_t)(m0 + wm * 128 + i * 16 + g * 4);
        const int col = n0 + wn * 64 + j * 16 + li;
#pragma unroll
        for (int r = 0; r < 4; ++r)
          C[(row + r) * DIM + col] = f2bf(acc[i][j][r] * qs);
      }
  } else {
    // V^T [n][m'] with per-32-run m-permutation (m = 32a+16s+4g+r -> 32a+8g+4s+r)
#pragma unroll
    for (int i = 0; i < 8; ++i)
#pragma unroll
      for (int j = 0; j < 4; ++j) {
        const int col = n0 + wn * 64 + j * 16 + li;
        const size_t rowb = (size_t)(m0 + wm * 128 + i * 16 + g * 4) + 4 * g - 12 * (i & 1);
        u32x2 w;
        w[0] = pkbf(acc[i][j][0], acc[i][j][1]);
        w[1] = pkbf(acc[i][j][2], acc[i][j][3]);
        *(u32x2*)(Vto + (size_t)col * MTOT + rowb) = w;
      }
  }
}

// ---------------- flash attention (unchanged from round 6) ----------------

#define KB 64
#define NT (SEQ/KB)

__global__ __launch_bounds__(512, 8)
void k_attn(const u16* __restrict__ Q, const u16* __restrict__ K,
            const u16* __restrict__ Vt, u16* __restrict__ O) {
  const int qt = blockIdx.x, bh = blockIdx.y;
  const int b = bh >> 4, h = bh & 15;
  const int q0 = qt * 128;
  const int tid = threadIdx.x, wid = tid >> 6, lane = tid & 63;
  const int g = lane >> 4, li = lane & 15;

  __shared__ u16 kl[2][KB * 64];
  __shared__ u16 vl[2][KB * 64];

  const size_t rb = (size_t)b * SEQ;
  const int hc = h * DKV;

  bf16x8 qf0, qf1;
  {
    const u16* qp = Q + (rb + q0 + wid * 16 + li) * DIM + hc;
    qf0 = *(const bf16x8*)(qp + g * 8);
    qf1 = *(const bf16x8*)(qp + 32 + g * 8);
  }

  bf16x8 ones;
#pragma unroll
  for (int j = 0; j < 8; ++j) ones[j] = (short)0x3F80;

  float mrun = -1e30f, lrun = 0.f;
  f32x4 o[4] = {};

  const int r8   = lane >> 3;
  const int swz  = ((lane & 7) ^ r8) * 8;
  const int srow = wid * 8 + r8;

  gload_lds16(K  + (rb + srow) * DIM + hc + swz,          &kl[0][wid * 512]);
  gload_lds16(Vt + (size_t)(hc + srow) * MTOT + rb + swz, &vl[0][wid * 512]);

  for (int it = 0; it < NT; ++it) {
    const int cur = it & 1;
    __syncthreads();

    if (it + 1 < NT) {
      const int n1 = (it + 1) * KB;
      gload_lds16(K  + (rb + n1 + srow) * DIM + hc + swz,          &kl[cur ^ 1][wid * 512]);
      gload_lds16(Vt + (size_t)(hc + srow) * MTOT + rb + n1 + swz, &vl[cur ^ 1][wid * 512]);
    }

    const u16* kb = kl[cur];
    const u16* vb = vl[cur];
    const int sw = (li & 7) << 3;

    f32x4 s[4];
    __builtin_amdgcn_s_setprio(1);
#pragma unroll
    for (int t = 0; t < 4; ++t) {
      const int row = t * 16 + li;
      bf16x8 kf0 = *(const bf16x8*)(kb + row * 64 + ((g * 8) ^ sw));
      bf16x8 kf1 = *(const bf16x8*)(kb + row * 64 + ((32 + g * 8) ^ sw));
      f32x4 z = {};
      z = __builtin_amdgcn_mfma_f32_16x16x32_bf16(kf0, qf0, z, 0, 0, 0);
      z = __builtin_amdgcn_mfma_f32_16x16x32_bf16(kf1, qf1, z, 0, 0, 0);
      s[t] = z;
    }
    __builtin_amdgcn_s_setprio(0);

    f32x4 mv = __builtin_elementwise_max(__builtin_elementwise_max(s[0], s[1]),
                                         __builtin_elementwise_max(s[2], s[3]));
    const float lmax = fmaxf(fmaxf(mv[0], mv[1]), fmaxf(mv[2], mv[3]));
    if (__any(lmax - mrun > THR)) {
      float pmax = fmaxf(lmax, __shfl_xor(lmax, 16));
      pmax = fmaxf(pmax, __shfl_xor(pmax, 32));
      const float mn = fmaxf(mrun, pmax);
      const float corr = __builtin_amdgcn_exp2f(mrun - mn);
      mrun = mn;
      lrun *= corr;
#pragma unroll
      for (int t = 0; t < 4; ++t) o[t] *= corr;
    }
    const float mb = mrun;
#pragma unroll
    for (int t = 0; t < 4; ++t)
#pragma unroll
      for (int r = 0; r < 4; ++r)
        s[t][r] = __builtin_amdgcn_exp2f(s[t][r] - mb);

    bf16x8 pa[2];
#pragma unroll
    for (int hh = 0; hh < 2; ++hh) {
      u32x4 pw;
      pw[0] = pkbf(s[2 * hh][0],     s[2 * hh][1]);
      pw[1] = pkbf(s[2 * hh][2],     s[2 * hh][3]);
      pw[2] = pkbf(s[2 * hh + 1][0], s[2 * hh + 1][1]);
      pw[3] = pkbf(s[2 * hh + 1][2], s[2 * hh + 1][3]);
      pa[hh] = __builtin_bit_cast(bf16x8, pw);
    }

    f32x4 zs = {};
    zs = __builtin_amdgcn_mfma_f32_16x16x32_bf16(ones, pa[0], zs, 0, 0, 0);
    zs = __builtin_amdgcn_mfma_f32_16x16x32_bf16(ones, pa[1], zs, 0, 0, 0);

    __builtin_amdgcn_s_setprio(1);
#pragma unroll
    for (int t = 0; t < 4; ++t) {
      const int row = t * 16 + li;
#pragma unroll
      for (int hh = 0; hh < 2; ++hh) {
        bf16x8 vf = *(const bf16x8*)(vb + row * 64 + ((hh * 32 + g * 8) ^ sw));
        o[t] = __builtin_amdgcn_mfma_f32_16x16x32_bf16(vf, pa[hh], o[t], 0, 0, 0);
      }
    }
    __builtin_amdgcn_s_setprio(0);

    lrun += zs[0];
  }

  {
    const float inv = 1.0f / lrun;
    const size_t qrow = rb + q0 + wid * 16 + li;
#pragma unroll
    for (int t = 0; t < 4; ++t) {
      u32x2 w;
      w[0] = pkbf(o[t][0] * inv, o[t][1] * inv);
      w[1] = pkbf(o[t][2] * inv, o[t][3] * inv);
      *(u32x2*)(O + qrow * DIM + hc + t * 16 + 4 * g) = w;
    }
  }
}

// ---------------- launch ----------------

extern "C" void kernel_launch(void* const* d_in, const int* in_sizes, int n_in,
                              void* d_out, int out_size, void* d_ws, size_t ws_size,
                              hipStream_t stream) {
  (void)in_sizes; (void)n_in; (void)out_size; (void)ws_size;
  const float* q  = (const float*)d_in[0];
  const float* Wq = (const float*)d_in[1];
  const float* Wk = (const float*)d_in[2];
  const float* Wv = (const float*)d_in[3];
  const float* Wo = (const float*)d_in[4];
  float* out = (float*)d_out;

  char* p = (char*)d_ws;
  u16* qb  = (u16*)p; p += (size_t)MTOT * DIM * 2;
  u16* wqt = (u16*)p; p += (size_t)DIM * DIM * 2;
  u16* wkt = (u16*)p; p += (size_t)DIM * DIM * 2;
  u16* wvt = (u16*)p; p += (size_t)DIM * DIM * 2;
  u16* wot = (u16*)p; p += (size_t)DIM * DIM * 2;
  u16* Qb  = (u16*)p; p += (size_t)MTOT * DIM * 2;
  u16* Kb  = (u16*)p; p += (size_t)MTOT * DIM * 2;
  u16* Vtb = (u16*)p; p += (size_t)MTOT * DIM * 2;
  u16* Hb  = Qb;   // heads reuse Q buffer (attn reads its Q tile to regs before writing same region)

  k_cvt_q<<<(MTOT * DIM / 4) / 256, 256, 0, stream>>>(q, qb);
  k_cvt_wproj<<<(DIM * DIM) / 256, 256, 0, stream>>>(Wq, wqt);
  k_cvt_wproj<<<(DIM * DIM) / 256, 256, 0, stream>>>(Wk, wkt);
  k_cvt_wproj<<<(DIM * DIM) / 256, 256, 0, stream>>>(Wv, wvt);
  k_cvt_wout<<<(DIM * DIM) / 256, 256, 0, stream>>>(Wo, wot);

  k_gemm_qkv8<<<dim3(MTOT / 256, 12), 512, 0, stream>>>(qb, wqt, wkt, wvt, Qb, Kb, Vtb);
  k_attn<<<dim3(SEQ / 128, BATCH * NHEAD), 512, 0, stream>>>(Qb, Kb, Vtb, Hb);
  k_gemm_out<<<dim3(MTOT / BM, DIM / BN), 256, 0, stream>>>(Hb, wot, out);
}

// Round 8
// 217.097 us; speedup vs baseline: 1.9267x; 1.0152x over previous
//
#include <hip/hip_runtime.h>
#include <hip/hip_bf16.h>
#include <stdint.h>
#include <math.h>

#define BATCH 4
#define SEQ   2048
#define NHEAD 16
#define DIM   1024
#define DKV   64
#define MTOT  (BATCH*SEQ)   // 8192

typedef __attribute__((ext_vector_type(8))) short  bf16x8;
typedef __attribute__((ext_vector_type(4))) float  f32x4;
typedef unsigned short u16;
typedef unsigned int   u32;
typedef __attribute__((ext_vector_type(4))) u16 u16x4;
typedef __attribute__((ext_vector_type(2))) u32 u32x2;
typedef __attribute__((ext_vector_type(4))) u32 u32x4;

// 0.125 (1/sqrt(dk)) * log2(e): folded into Q so attention runs exp2-domain.
#define QSCALE 0.18033688011112042f
#define THR    8.0f

__device__ __forceinline__ u16 f2bf(float f) {
  __hip_bfloat16 h = __float2bfloat16(f);
  u16 r;
  __builtin_memcpy(&r, &h, 2);
  return r;
}
__device__ __forceinline__ u32 pkbf(float lo, float hi) {
  __hip_bfloat162 h = __float22bfloat162_rn(float2{lo, hi});
  u32 r;
  __builtin_memcpy(&r, &h, 4);
  return r;
}

__device__ __forceinline__ void gload_lds16(const void* g, void* l) {
  __builtin_amdgcn_global_load_lds((u32 __attribute__((address_space(1)))*)(g),
                                   (u32 __attribute__((address_space(3)))*)(l),
                                   16, 0, 0);
}

// ---------------- conversions ----------------

__global__ void k_cvt_q(const float* __restrict__ src, u16* __restrict__ dst) {
  const int i = (blockIdx.x * 256 + threadIdx.x) * 4;
  float4 v = *(const float4*)(src + i);
  u32x2 o;
  o[0] = pkbf(v.x, v.y); o[1] = pkbf(v.z, v.w);
  *(u32x2*)(dst + i) = o;
}

__global__ void k_cvt_wproj(const float* __restrict__ w, u16* __restrict__ wt) {
  const int idx = blockIdx.x * 256 + threadIdx.x;
  const int n = idx >> 10, d = idx & 1023;
  wt[idx] = f2bf(w[((n >> 6) << 16) + (d << 6) + (n & 63)]);
}

__global__ void k_cvt_wout(const float* __restrict__ w, u16* __restrict__ wt) {
  const int idx = blockIdx.x * 256 + threadIdx.x;
  const int e = idx >> 10, hv = idx & 1023;
  wt[idx] = f2bf(w[(hv << 10) + e]);
}

// ---------------- pipelined 256x128 GEMM (4-phase, counted vmcnt) ----------------
// BM=256, BN=128, BK=64, 8 waves (4M x 2N), per-wave C = 64x64 (M_rep=4, N_rep=4).
// LDS 96KB: A [2 buf][2 k-half][256x32], B [2 buf][2 k-half][128x32] (bf16).
// Swizzle: lin_elem ^= ((lin>>6)&7)<<3, applied as inverse-swizzled per-lane
// global source (linear gload_lds dest) + matching XOR on ds_read addr.
// Schedule per K-tile kt (cur=kt&1, 4 phases = ks x m-half):
//  ph1 stages (kt+1).h1-A -> buf[cur^1], ph2 stages (kt+1).h1-B, vmcnt(3)
//  ph3 stages (kt+2).h0-A -> buf[cur]   (region dead), ph4 (kt+2).h0-B, vmcnt(3)
// Half-tile = 3 loads/thread (A 2 + B 1); prologue 9 loads, vmcnt(6).
// MODE: 0 = bf16 C[m][n], 1 = f32 C[m][n], 2 = bf16 * QSCALE,
//       3 = bf16 V^T [n][m'] with per-32-run m-permutation (PV k-order baked in).

template<int MODE>
__device__ __forceinline__ void gemm2(u16* __restrict__ sm,
                                      const u16* __restrict__ A, const u16* __restrict__ Bt,
                                      void* __restrict__ Cp, int m0, int n0) {
  const int tid = threadIdx.x, wid = tid >> 6, lane = tid & 63;
  const int g = lane >> 4, li = lane & 15;
  const int wm = wid >> 1, wn = wid & 1;

  // --- staging addresses (inverse-swizzled global source, linear LDS dest) ---
  const int c0 = wid * 128 + lane, c1 = c0 + 64;          // A chunks (1024/half)
  const int s0 = (c0 * 8) ^ (((c0 >> 3) & 7) << 3);
  const int s1 = (c1 * 8) ^ (((c1 >> 3) & 7) << 3);
  const int cB = tid;                                     // B chunks (512/half)
  const int sB = (cB * 8) ^ (((cB >> 3) & 7) << 3);
  const u16* As0 = A  + (size_t)(m0 + (s0 >> 5)) * DIM + (s0 & 31);
  const u16* As1 = A  + (size_t)(m0 + (s1 >> 5)) * DIM + (s1 & 31);
  const u16* Bs  = Bt + (size_t)(n0 + (sB >> 5)) * DIM + (sB & 31);
  u16* dA0 = sm + wid * 1024;
  u16* dA1 = sm + wid * 1024 + 512;
  u16* dB  = sm + 32768 + wid * 512;

#define SA2(t, ks, tb) do { \
    gload_lds16(As0 + (t) * 64 + (ks) * 32, dA0 + (tb) * 16384 + (ks) * 8192); \
    gload_lds16(As1 + (t) * 64 + (ks) * 32, dA1 + (tb) * 16384 + (ks) * 8192); } while (0)
#define SB2(t, ks, tb) \
    gload_lds16(Bs + (t) * 64 + (ks) * 32, dB + (tb) * 8192 + (ks) * 4096)

  // --- read bases (swizzled) ---
  const int vx = ((li >> 1) & 7) << 3;
  const int a_rd = (((wm * 64 + li) * 32) + g * 8) ^ vx;          // + i*512 + ks*8192
  const int b_rd = (((wn * 64 + li) * 32) + g * 8) ^ vx;          // + j*512 + ks*4096

  f32x4 acc[4][4] = {};

  // prologue: t0.h0, t0.h1, t1.h0 (9 loads); ensure t0.h0 done
  SA2(0, 0, 0); SB2(0, 0, 0);
  SA2(0, 1, 0); SB2(0, 1, 0);
  SA2(1, 0, 1); SB2(1, 0, 1);
  asm volatile("s_waitcnt vmcnt(6)" ::: "memory");
  __builtin_amdgcn_s_barrier();

#pragma unroll 2
  for (int kt = 0; kt < 16; ++kt) {
    const int cur = kt & 1, t1 = (kt + 1) & 15, t2 = (kt + 2) & 15;
    const u16* pa = sm + cur * 16384 + a_rd;
    const u16* pb = sm + 32768 + cur * 8192 + b_rd;
    bf16x8 af[2], bfq[4];

    // ---- phase 1: ks0, m-reps 0-1
#pragma unroll
    for (int j = 0; j < 4; ++j) bfq[j] = *(const bf16x8*)(pb + j * 512);
    af[0] = *(const bf16x8*)(pa);
    af[1] = *(const bf16x8*)(pa + 512);
    SA2(t1, 1, cur ^ 1);
    __builtin_amdgcn_s_barrier();
    __builtin_amdgcn_s_setprio(1);
#pragma unroll
    for (int i = 0; i < 2; ++i)
#pragma unroll
      for (int j = 0; j < 4; ++j)
        acc[i][j] = __builtin_amdgcn_mfma_f32_16x16x32_bf16(af[i], bfq[j], acc[i][j], 0, 0, 0);
    __builtin_amdgcn_s_setprio(0);
    __builtin_amdgcn_s_barrier();

    // ---- phase 2: ks0, m-reps 2-3
    af[0] = *(const bf16x8*)(pa + 2 * 512);
    af[1] = *(const bf16x8*)(pa + 3 * 512);
    SB2(t1, 1, cur ^ 1);
    __builtin_amdgcn_s_barrier();
    __builtin_amdgcn_s_setprio(1);
#pragma unroll
    for (int i = 0; i < 2; ++i)
#pragma unroll
      for (int j = 0; j < 4; ++j)
        acc[i + 2][j] = __builtin_amdgcn_mfma_f32_16x16x32_bf16(af[i], bfq[j], acc[i + 2][j], 0, 0, 0);
    __builtin_amdgcn_s_setprio(0);
    asm volatile("s_waitcnt vmcnt(3)" ::: "memory");
    __builtin_amdgcn_s_barrier();

    // ---- phase 3: ks1, m-reps 0-1
#pragma unroll
    for (int j = 0; j < 4; ++j) bfq[j] = *(const bf16x8*)(pb + 4096 + j * 512);
    af[0] = *(const bf16x8*)(pa + 8192);
    af[1] = *(const bf16x8*)(pa + 8192 + 512);
    SA2(t2, 0, cur);
    __builtin_amdgcn_s_barrier();
    __builtin_amdgcn_s_setprio(1);
#pragma unroll
    for (int i = 0; i < 2; ++i)
#pragma unroll
      for (int j = 0; j < 4; ++j)
        acc[i][j] = __builtin_amdgcn_mfma_f32_16x16x32_bf16(af[i], bfq[j], acc[i][j], 0, 0, 0);
    __builtin_amdgcn_s_setprio(0);
    __builtin_amdgcn_s_barrier();

    // ---- phase 4: ks1, m-reps 2-3
    af[0] = *(const bf16x8*)(pa + 8192 + 2 * 512);
    af[1] = *(const bf16x8*)(pa + 8192 + 3 * 512);
    SB2(t2, 0, cur);
    __builtin_amdgcn_s_barrier();
    __builtin_amdgcn_s_setprio(1);
#pragma unroll
    for (int i = 0; i < 2; ++i)
#pragma unroll
      for (int j = 0; j < 4; ++j)
        acc[i + 2][j] = __builtin_amdgcn_mfma_f32_16x16x32_bf16(af[i], bfq[j], acc[i + 2][j], 0, 0, 0);
    __builtin_amdgcn_s_setprio(0);
    asm volatile("s_waitcnt vmcnt(3)" ::: "memory");
    __builtin_amdgcn_s_barrier();
  }
#undef SA2
#undef SB2

  // ---- epilogue ----
#pragma unroll
  for (int i = 0; i < 4; ++i)
#pragma unroll
    for (int j = 0; j < 4; ++j) {
      const int col = n0 + wn * 64 + j * 16 + li;
      if (MODE == 3) {
        const size_t rowb = (size_t)(m0 + wm * 64 + i * 16 + g * 4) + 4 * g - 12 * (i & 1);
        u32x2 w;
        w[0] = pkbf(acc[i][j][0], acc[i][j][1]);
        w[1] = pkbf(acc[i][j][2], acc[i][j][3]);
        *(u32x2*)((u16*)Cp + (size_t)col * MTOT + rowb) = w;
      } else if (MODE == 1) {
#pragma unroll
        for (int r = 0; r < 4; ++r) {
          const size_t row = (size_t)(m0 + wm * 64 + i * 16 + g * 4 + r);
          ((float*)Cp)[row * DIM + col] = acc[i][j][r];
        }
      } else {
#pragma unroll
        for (int r = 0; r < 4; ++r) {
          const size_t row = (size_t)(m0 + wm * 64 + i * 16 + g * 4 + r);
          float v = acc[i][j][r];
          if (MODE == 2) v *= QSCALE;
          ((u16*)Cp)[row * DIM + col] = f2bf(v);
        }
      }
    }
}

__global__ __launch_bounds__(512, 2)
void k_gemm_qkv2(const u16* __restrict__ A, const u16* __restrict__ wq,
                 const u16* __restrict__ wk, const u16* __restrict__ wv,
                 u16* __restrict__ Qo, u16* __restrict__ Ko, u16* __restrict__ Vto) {
  __shared__ u16 sm[49152];
  const int m0 = blockIdx.x * 256;
  const int yt = blockIdx.y;
  const int wsel = yt >> 3;
  const int n0 = (yt & 7) * 128;
  if (wsel == 0)      gemm2<2>(sm, A, wq, Qo,  m0, n0);
  else if (wsel == 1) gemm2<0>(sm, A, wk, Ko,  m0, n0);
  else                gemm2<3>(sm, A, wv, Vto, m0, n0);
}

__global__ __launch_bounds__(512, 2)
void k_gemm_out2(const u16* __restrict__ A, const u16* __restrict__ Bt, float* __restrict__ C) {
  __shared__ u16 sm[49152];
  gemm2<1>(sm, A, Bt, C, blockIdx.x * 256, blockIdx.y * 128);
}

// ---------------- flash attention (unchanged from round 6) ----------------

#define KB 64
#define NT (SEQ/KB)

__global__ __launch_bounds__(512, 8)
void k_attn(const u16* __restrict__ Q, const u16* __restrict__ K,
            const u16* __restrict__ Vt, u16* __restrict__ O) {
  const int qt = blockIdx.x, bh = blockIdx.y;
  const int b = bh >> 4, h = bh & 15;
  const int q0 = qt * 128;
  const int tid = threadIdx.x, wid = tid >> 6, lane = tid & 63;
  const int g = lane >> 4, li = lane & 15;

  __shared__ u16 kl[2][KB * 64];
  __shared__ u16 vl[2][KB * 64];

  const size_t rb = (size_t)b * SEQ;
  const int hc = h * DKV;

  bf16x8 qf0, qf1;
  {
    const u16* qp = Q + (rb + q0 + wid * 16 + li) * DIM + hc;
    qf0 = *(const bf16x8*)(qp + g * 8);
    qf1 = *(const bf16x8*)(qp + 32 + g * 8);
  }

  bf16x8 ones;
#pragma unroll
  for (int j = 0; j < 8; ++j) ones[j] = (short)0x3F80;

  float mrun = -1e30f, lrun = 0.f;
  f32x4 o[4] = {};

  const int r8   = lane >> 3;
  const int swz  = ((lane & 7) ^ r8) * 8;
  const int srow = wid * 8 + r8;

  gload_lds16(K  + (rb + srow) * DIM + hc + swz,          &kl[0][wid * 512]);
  gload_lds16(Vt + (size_t)(hc + srow) * MTOT + rb + swz, &vl[0][wid * 512]);

  for (int it = 0; it < NT; ++it) {
    const int cur = it & 1;
    __syncthreads();

    if (it + 1 < NT) {
      const int n1 = (it + 1) * KB;
      gload_lds16(K  + (rb + n1 + srow) * DIM + hc + swz,          &kl[cur ^ 1][wid * 512]);
      gload_lds16(Vt + (size_t)(hc + srow) * MTOT + rb + n1 + swz, &vl[cur ^ 1][wid * 512]);
    }

    const u16* kb = kl[cur];
    const u16* vb = vl[cur];
    const int sw = (li & 7) << 3;

    f32x4 s[4];
    __builtin_amdgcn_s_setprio(1);
#pragma unroll
    for (int t = 0; t < 4; ++t) {
      const int row = t * 16 + li;
      bf16x8 kf0 = *(const bf16x8*)(kb + row * 64 + ((g * 8) ^ sw));
      bf16x8 kf1 = *(const bf16x8*)(kb + row * 64 + ((32 + g * 8) ^ sw));
      f32x4 z = {};
      z = __builtin_amdgcn_mfma_f32_16x16x32_bf16(kf0, qf0, z, 0, 0, 0);
      z = __builtin_amdgcn_mfma_f32_16x16x32_bf16(kf1, qf1, z, 0, 0, 0);
      s[t] = z;
    }
    __builtin_amdgcn_s_setprio(0);

    f32x4 mv = __builtin_elementwise_max(__builtin_elementwise_max(s[0], s[1]),
                                         __builtin_elementwise_max(s[2], s[3]));
    const float lmax = fmaxf(fmaxf(mv[0], mv[1]), fmaxf(mv[2], mv[3]));
    if (__any(lmax - mrun > THR)) {
      float pmax = fmaxf(lmax, __shfl_xor(lmax, 16));
      pmax = fmaxf(pmax, __shfl_xor(pmax, 32));
      const float mn = fmaxf(mrun, pmax);
      const float corr = __builtin_amdgcn_exp2f(mrun - mn);
      mrun = mn;
      lrun *= corr;
#pragma unroll
      for (int t = 0; t < 4; ++t) o[t] *= corr;
    }
    const float mb = mrun;
#pragma unroll
    for (int t = 0; t < 4; ++t)
#pragma unroll
      for (int r = 0; r < 4; ++r)
        s[t][r] = __builtin_amdgcn_exp2f(s[t][r] - mb);

    bf16x8 pa[2];
#pragma unroll
    for (int hh = 0; hh < 2; ++hh) {
      u32x4 pw;
      pw[0] = pkbf(s[2 * hh][0],     s[2 * hh][1]);
      pw[1] = pkbf(s[2 * hh][2],     s[2 * hh][3]);
      pw[2] = pkbf(s[2 * hh + 1][0], s[2 * hh + 1][1]);
      pw[3] = pkbf(s[2 * hh + 1][2], s[2 * hh + 1][3]);
      pa[hh] = __builtin_bit_cast(bf16x8, pw);
    }

    f32x4 zs = {};
    zs = __builtin_amdgcn_mfma_f32_16x16x32_bf16(ones, pa[0], zs, 0, 0, 0);
    zs = __builtin_amdgcn_mfma_f32_16x16x32_bf16(ones, pa[1], zs, 0, 0, 0);

    __builtin_amdgcn_s_setprio(1);
#pragma unroll
    for (int t = 0; t < 4; ++t) {
      const int row = t * 16 + li;
#pragma unroll
      for (int hh = 0; hh < 2; ++hh) {
        bf16x8 vf = *(const bf16x8*)(vb + row * 64 + ((hh * 32 + g * 8) ^ sw));
        o[t] = __builtin_amdgcn_mfma_f32_16x16x32_bf16(vf, pa[hh], o[t], 0, 0, 0);
      }
    }
    __builtin_amdgcn_s_setprio(0);

    lrun += zs[0];
  }

  {
    const float inv = 1.0f / lrun;
    const size_t qrow = rb + q0 + wid * 16 + li;
#pragma unroll
    for (int t = 0; t < 4; ++t) {
      u32x2 w;
      w[0] = pkbf(o[t][0] * inv, o[t][1] * inv);
      w[1] = pkbf(o[t][2] * inv, o[t][3] * inv);
      *(u32x2*)(O + qrow * DIM + hc + t * 16 + 4 * g) = w;
    }
  }
}

// ---------------- launch ----------------

extern "C" void kernel_launch(void* const* d_in, const int* in_sizes, int n_in,
                              void* d_out, int out_size, void* d_ws, size_t ws_size,
                              hipStream_t stream) {
  (void)in_sizes; (void)n_in; (void)out_size; (void)ws_size;
  const float* q  = (const float*)d_in[0];
  const float* Wq = (const float*)d_in[1];
  const float* Wk = (const float*)d_in[2];
  const float* Wv = (const float*)d_in[3];
  const float* Wo = (const float*)d_in[4];
  float* out = (float*)d_out;

  char* p = (char*)d_ws;
  u16* qb  = (u16*)p; p += (size_t)MTOT * DIM * 2;
  u16* wqt = (u16*)p; p += (size_t)DIM * DIM * 2;
  u16* wkt = (u16*)p; p += (size_t)DIM * DIM * 2;
  u16* wvt = (u16*)p; p += (size_t)DIM * DIM * 2;
  u16* wot = (u16*)p; p += (size_t)DIM * DIM * 2;
  u16* Qb  = (u16*)p; p += (size_t)MTOT * DIM * 2;
  u16* Kb  = (u16*)p; p += (size_t)MTOT * DIM * 2;
  u16* Vtb = (u16*)p; p += (size_t)MTOT * DIM * 2;
  u16* Hb  = Qb;   // heads reuse Q buffer (attn reads its Q tile to regs before writing same region)

  k_cvt_q<<<(MTOT * DIM / 4) / 256, 256, 0, stream>>>(q, qb);
  k_cvt_wproj<<<(DIM * DIM) / 256, 256, 0, stream>>>(Wq, wqt);
  k_cvt_wproj<<<(DIM * DIM) / 256, 256, 0, stream>>>(Wk, wkt);
  k_cvt_wproj<<<(DIM * DIM) / 256, 256, 0, stream>>>(Wv, wvt);
  k_cvt_wout<<<(DIM * DIM) / 256, 256, 0, stream>>>(Wo, wot);

  k_gemm_qkv2<<<dim3(MTOT / 256, 24), 512, 0, stream>>>(qb, wqt, wkt, wvt, Qb, Kb, Vtb);
  k_attn<<<dim3(SEQ / 128, BATCH * NHEAD), 512, 0, stream>>>(Qb, Kb, Vtb, Hb);
  k_gemm_out2<<<dim3(MTOT / 256, DIM / 128), 512, 0, stream>>>(Hb, wot, out);
}